// Round 3
// baseline (1855.466 us; speedup 1.0000x reference)
//
#include <hip/hip_runtime.h>

#define VOCAB 8192
#define DIM   256
#define NTOK  32768          // 8*4096

// d_out layout (floats): quantised[8388608], loss, codebook_loss, idx[32768] (as float)
#define LOSS_OFF 8388608
#define CB_OFF   8388609
#define IDX_OFF  8388610

// d_ws layout (floats): x2[32768] | e2[8192] | acc
#define WS_X2  0
#define WS_E2  32768
#define WS_ACC 40960

#define BM 128
#define BV 256
#define BK 32

// ---------------------------------------------------------------------------
// Row sum-of-squares replicating numpy pairwise_sum order for n=256:
//   P256(a) = P128(a[0:128]) + P128(a[128:256])
//   P128(b) = ((r0+r1)+(r2+r3))+((r4+r5)+(r6+r7)), r_k = seq sum of b[k+8i]
// Rows 0..NTOK-1 -> x2, rows NTOK..NTOK+VOCAB-1 -> e2. ws[row] matches layout.
__global__ __launch_bounds__(256) void k_sums(const float* __restrict__ x,
                                              const float* __restrict__ emb,
                                              float* __restrict__ ws) {
    const int lane = threadIdx.x & 63;
    const int wave = threadIdx.x >> 6;
    const int row  = blockIdx.x * 16 + wave * 4 + (lane >> 4);
    const int sub  = lane & 15;
    const int k    = sub & 7;
    const int half = sub >> 3;
    const float* src = (row < NTOK ? x + (size_t)row * DIM
                                   : emb + (size_t)(row - NTOK) * DIM)
                       + half * 128 + k;
    float r;
    {
        float v0 = src[0];
        float t0 = v0 * v0;
        asm volatile("" : "+v"(t0));     // block contraction: need fl(v*v) then fl(add)
        r = t0;
        for (int i = 1; i < 16; ++i) {
            float w = src[8 * i];
            float u = w * w;
            asm volatile("" : "+v"(u));
            r = r + u;
        }
    }
    float t;
    t = __shfl_xor(r, 1, 64); r = r + t;   // (r_k + r_{k^1}): commutative, bit-equal both lanes
    t = __shfl_xor(r, 2, 64); r = r + t;   // (r0+r1)+(r2+r3)
    t = __shfl_xor(r, 4, 64); r = r + t;   // P128
    t = __shfl_xor(r, 8, 64); r = r + t;   // P128_lo + P128_hi = P256
    if (sub == 0) ws[row] = r;
    if (blockIdx.x == 0 && threadIdx.x == 0) ws[WS_ACC] = 0.0f;
}

// ---------------------------------------------------------------------------
// Fused distance GEMM + fp32 ref-semantics argmin (first-occurrence tie-break).
// score_v = fl( fl(x2_tok + e2_v) - fl(2*dot_v) )   [2*dot exact -> fma-safe]
__global__ __launch_bounds__(512) void k_main(
        const float* __restrict__ x, const float* __restrict__ emb,
        const float* __restrict__ x2, const float* __restrict__ e2,
        float* __restrict__ idxf) {
    __shared__ float xT[BK][132];   // padded: conflict-free transposed stores
    __shared__ float eT[BK][260];

    const int tid = threadIdx.x;
    const int tx = tid & 31, ty = tid >> 5;   // 32 x 16 thread grid
    const int t0 = blockIdx.x * BM;

    float x2r[8];
#pragma unroll
    for (int ii = 0; ii < 8; ++ii)
        x2r[ii] = x2[t0 + ((ii & 4) << 4) + ty * 4 + (ii & 3)];

    float tb[8]; int ti[8];
#pragma unroll
    for (int s = 0; s < 8; ++s) { tb[s] = 3.0e38f; ti[s] = 0; }

    const int xt = tid & 127, xc = tid >> 7;     // x-staging role
    const int ev = tid & 255, ec0 = tid >> 8;    // e-staging role

    for (int v0 = 0; v0 < VOCAB; v0 += BV) {
        float a[8][8];
#pragma unroll
        for (int i = 0; i < 8; ++i)
#pragma unroll
            for (int j = 0; j < 8; ++j) a[i][j] = 0.0f;

        for (int kk = 0; kk < DIM; kk += BK) {
            __syncthreads();   // protect LDS from previous iteration's readers
#pragma unroll
            for (int h = 0; h < 2; ++h) {
                const int kc = h * 16 + xc * 4;
                const float4 vx = *(const float4*)&x[(size_t)(t0 + xt) * DIM + kk + kc];
                xT[kc + 0][xt] = vx.x; xT[kc + 1][xt] = vx.y;
                xT[kc + 2][xt] = vx.z; xT[kc + 3][xt] = vx.w;
            }
#pragma unroll
            for (int h = 0; h < 4; ++h) {
                const int kc = (ec0 + 2 * h) * 4;
                const float4 ve = *(const float4*)&emb[(size_t)(v0 + ev) * DIM + kk + kc];
                eT[kc + 0][ev] = ve.x; eT[kc + 1][ev] = ve.y;
                eT[kc + 2][ev] = ve.z; eT[kc + 3][ev] = ve.w;
            }
            __syncthreads();
#pragma unroll 4
            for (int k = 0; k < BK; ++k) {
                float xa[8], eb[8];
                *(float4*)&xa[0] = *(const float4*)&xT[k][ty * 4];
                *(float4*)&xa[4] = *(const float4*)&xT[k][64 + ty * 4];
                *(float4*)&eb[0] = *(const float4*)&eT[k][tx * 4];
                *(float4*)&eb[4] = *(const float4*)&eT[k][128 + tx * 4];
#pragma unroll
                for (int i = 0; i < 8; ++i)
#pragma unroll
                    for (int j = 0; j < 8; ++j)
                        a[i][j] = fmaf(xa[i], eb[j], a[i][j]);
            }
        }
        // fp32 ref-semantics scoring; strict < keeps first (lowest-v) min
#pragma unroll
        for (int jj = 0; jj < 8; ++jj) {
            const int v = v0 + ((jj & 4) << 5) + tx * 4 + (jj & 3);
            const float evv = e2[v];
#pragma unroll
            for (int ii = 0; ii < 8; ++ii) {
                const float A  = x2r[ii] + evv;          // fl(x2 + e2)
                const float sc = A - 2.0f * a[ii][jj];   // fl(A - fl(2*dot)); 2*dot exact
                if (sc < tb[ii]) { tb[ii] = sc; ti[ii] = v; }
            }
        }
    }
    // merge across the 32 tx lanes: min score, ties -> lowest index
#pragma unroll
    for (int ii = 0; ii < 8; ++ii) {
        float b = tb[ii]; int bi = ti[ii];
#pragma unroll
        for (int m = 1; m < 32; m <<= 1) {
            const float ob = __shfl_xor(b, m, 64);
            const int   oi = __shfl_xor(bi, m, 64);
            if (ob < b || (ob == b && oi < bi)) { b = ob; bi = oi; }
        }
        if (tx == 0) {
            const int token = t0 + ((ii & 4) << 4) + ty * 4 + (ii & 3);
            idxf[token] = (float)bi;
        }
    }
}

// --------------------------------------- gather quantised + loss reduction
__global__ __launch_bounds__(256) void k_gather(
        const float* __restrict__ x, const float* __restrict__ emb,
        const float* __restrict__ idxf, float* __restrict__ qout,
        float* __restrict__ acc) {
    const int token = blockIdx.x * 4 + (threadIdx.x >> 6);
    const int lane  = threadIdx.x & 63;
    const int v = (int)idxf[token];
    const float4 e4 = *(const float4*)&emb[(size_t)v * DIM + lane * 4];
    const float4 x4 = *(const float4*)&x[(size_t)token * DIM + lane * 4];
    *(float4*)&qout[(size_t)token * DIM + lane * 4] = e4;
    const float dx = e4.x - x4.x, dy = e4.y - x4.y, dz = e4.z - x4.z, dw = e4.w - x4.w;
    float s = dx*dx + dy*dy + dz*dz + dw*dw;
#pragma unroll
    for (int m = 1; m < 64; m <<= 1) s += __shfl_xor(s, m, 64);
    __shared__ float wsum[4];
    if (lane == 0) wsum[threadIdx.x >> 6] = s;
    __syncthreads();
    if (threadIdx.x == 0) atomicAdd(acc, wsum[0] + wsum[1] + wsum[2] + wsum[3]);
}

__global__ void k_final(const float* __restrict__ acc, float* __restrict__ out) {
    const float cb = *acc * (1.0f / 8388608.0f);
    out[LOSS_OFF] = 1.25f * cb;   // codebook + 0.25 * e_latent, numerically equal terms
    out[CB_OFF]   = cb;
}

// --------------------------------------------------------------- launcher
extern "C" void kernel_launch(void* const* d_in, const int* in_sizes, int n_in,
                              void* d_out, int out_size, void* d_ws, size_t ws_size,
                              hipStream_t stream) {
    const float* x   = (const float*)d_in[0];
    const float* emb = (const float*)d_in[1];
    float* out  = (float*)d_out;
    float* wsF  = (float*)d_ws;
    float* x2   = wsF + WS_X2;
    float* e2   = wsF + WS_E2;
    float* acc  = wsF + WS_ACC;
    float* idxf = out + IDX_OFF;

    k_sums  <<<(NTOK + VOCAB) / 16, 256, 0, stream>>>(x, emb, wsF);
    k_main  <<<NTOK / BM, 512, 0, stream>>>(x, emb, x2, e2, idxf);
    k_gather<<<NTOK / 4, 256, 0, stream>>>(x, emb, idxf, out, acc);
    k_final <<<1, 1, 0, stream>>>(acc, out);
}

// Round 4
// 1041.835 us; speedup vs baseline: 1.7810x; 1.7810x over previous
//
#include <hip/hip_runtime.h>

#define VOCAB 8192
#define DIM   256
#define NTOK  32768          // 8*4096

// d_out layout (floats): quantised[8388608], loss, codebook_loss, idx[32768] (as float)
#define LOSS_OFF 8388608
#define CB_OFF   8388609
#define IDX_OFF  8388610

// ---- ws layout (bytes) ----
#define X2_F     0            // float[32768]   (f32 index)
#define E2_F     32768        // float[8192]
#define ACC_F    40960        // float
#define CNT_I    40961        // int
#define OVF_I    40962        // int
#define BEST_B   196608       // u64[32768]   -> ends 458752
#define EMB16_B  458752       // bf16[8192*256] = 4 MiB -> ends 4653056
#define SMAX_B   4718592      // float[256][32768] = 32 MiB -> ends 38273024
#define THR_B    38273024     // float[32768] -> ends 38404096
#define LIST_B   38404096     // u32[CAP]
#define CAP      4194304
#define WS_NEED  (LIST_B + CAP * 4)   // 55,181,312 bytes

#define M2 1.5e-4f            // dot-space rescue margin (err budget ~3.5e-5, 4x headroom)

typedef __attribute__((ext_vector_type(8)))  short bf16x8;
typedef __attribute__((ext_vector_type(16))) float f32x16;

// ===========================================================================
// k_sums: numpy pairwise-exact x2/e2 (proven in round 3) + init scalars/best
__global__ __launch_bounds__(256) void k_sums(const float* __restrict__ x,
                                              const float* __restrict__ emb,
                                              float* __restrict__ ws,
                                              unsigned long long* __restrict__ best,
                                              int full) {
    const int lane = threadIdx.x & 63;
    const int wave = threadIdx.x >> 6;
    const int row  = blockIdx.x * 16 + wave * 4 + (lane >> 4);
    const int sub  = lane & 15;
    const int k    = sub & 7;
    const int half = sub >> 3;
    const float* src = (row < NTOK ? x + (size_t)row * DIM
                                   : emb + (size_t)(row - NTOK) * DIM)
                       + half * 128 + k;
    float r;
    {
        float v0 = src[0];
        float t0 = v0 * v0;
        asm volatile("" : "+v"(t0));     // block fma contraction
        r = t0;
        for (int i = 1; i < 16; ++i) {
            float w = src[8 * i];
            float u = w * w;
            asm volatile("" : "+v"(u));
            r = r + u;
        }
    }
    float t;
    t = __shfl_xor(r, 1, 64); r = r + t;
    t = __shfl_xor(r, 2, 64); r = r + t;
    t = __shfl_xor(r, 4, 64); r = r + t;
    t = __shfl_xor(r, 8, 64); r = r + t;
    if (sub == 0) ws[row] = r;
    const int gid = blockIdx.x * 256 + threadIdx.x;
    if (gid == 0) {
        ws[ACC_F] = 0.0f;
        ((int*)ws)[CNT_I] = 0;
        ((int*)ws)[OVF_I] = 0;
    }
    if (full && gid < NTOK) best[gid] = ~0ULL;
}

// ===========================================================================
// k_cvt: emb fp32 -> bf16 (truncate; margin absorbs the bias)
__global__ __launch_bounds__(256) void k_cvt(const float* __restrict__ emb,
                                             unsigned* __restrict__ out) {
    const int i = blockIdx.x * 256 + threadIdx.x;      // 524288 threads x 4 floats
    const float4 f = *(const float4*)(emb + (size_t)i * 4);
    unsigned b0 = __float_as_uint(f.x), b1 = __float_as_uint(f.y);
    unsigned b2 = __float_as_uint(f.z), b3 = __float_as_uint(f.w);
    uint2 o;
    o.x = (b1 & 0xFFFF0000u) | (b0 >> 16);
    o.y = (b3 & 0xFFFF0000u) | (b2 >> 16);
    *(uint2*)(out + (size_t)i * 2) = o;
}

// ===========================================================================
// k_coarse: bf16 MFMA max-dot per (token, 32-code tile) + per-token threshold
//  block = 128 tokens, 8 waves = (g in {0,1} token-halves) x (csub 0..3 code slices)
//  chunk = 128 codes staged in LDS (double-buffered), x held in register B-frags
#define STAGE(BUFI, N) do {                                                    \
    const char* _src = (const char*)embh + ((size_t)(N) << 16);                \
    _Pragma("unroll")                                                          \
    for (int _r = 0; _r < 8; ++_r) {                                           \
        unsigned _o  = (unsigned)tid * 16u + (unsigned)_r * 8192u;             \
        unsigned _so = (_o & ~511u) | ((_o & 511u) ^ (((_o >> 9) & 7u) << 4)); \
        __builtin_amdgcn_global_load_lds(                                      \
            (const __attribute__((address_space(1))) void*)(_src + _so),       \
            (__attribute__((address_space(3))) void*)(&ebuf[(BUFI)][_o]),      \
            16, 0, 0);                                                         \
    }                                                                          \
} while (0)

__device__ __forceinline__ unsigned f_ord(float v) {
    unsigned u = __float_as_uint(v);
    return u ^ ((unsigned)((int)u >> 31) | 0x80000000u);
}
__device__ __forceinline__ float f_unord(unsigned k) {
    unsigned m = (k >> 31) ? 0x80000000u : 0xFFFFFFFFu;
    return __uint_as_float(k ^ m);
}

__global__ __launch_bounds__(512, 2) void k_coarse(
        const float* __restrict__ x, const unsigned short* __restrict__ embh,
        float* __restrict__ smax, float* __restrict__ thr) {
    __shared__ char ebuf[2][65536];
    __shared__ unsigned tmax[128];

    const int tid  = threadIdx.x;
    const int lane = tid & 63, wid = tid >> 6;
    const int g = wid & 1, csub = wid >> 1;
    const int t_wave = blockIdx.x * 128 + g * 64;

    // ---- persistent x B-frags: bx[grp][kt], token col = lane&31, k = kt*16+(lane>>5)*8+j
    bf16x8 bx[2][16];
    {
        const int tok0 = t_wave + (lane & 31);
#pragma unroll
        for (int grp = 0; grp < 2; ++grp) {
            const float* xr = x + (size_t)(tok0 + grp * 32) * DIM + (lane >> 5) * 8;
#pragma unroll
            for (int kt = 0; kt < 16; ++kt) {
                float4 f0 = *(const float4*)(xr + kt * 16);
                float4 f1 = *(const float4*)(xr + kt * 16 + 4);
                union { bf16x8 v; unsigned u[4]; } P;
                P.u[0] = (__float_as_uint(f0.y) & 0xFFFF0000u) | (__float_as_uint(f0.x) >> 16);
                P.u[1] = (__float_as_uint(f0.w) & 0xFFFF0000u) | (__float_as_uint(f0.z) >> 16);
                P.u[2] = (__float_as_uint(f1.y) & 0xFFFF0000u) | (__float_as_uint(f1.x) >> 16);
                P.u[3] = (__float_as_uint(f1.w) & 0xFFFF0000u) | (__float_as_uint(f1.z) >> 16);
                bx[grp][kt] = P.v;
            }
        }
    }

    // A-read address: row_local = csub*32 + lane&31 ; col bytes = kt*32 + (lane>>5)*16
    const unsigned rl    = (unsigned)(csub * 32 + (lane & 31));
    const unsigned abase = rl * 512u + (unsigned)((lane >> 5) * 16);
    const unsigned sw    = (rl & 7u) << 4;

    STAGE(0, 0);
    asm volatile("s_waitcnt vmcnt(0)");
    __syncthreads();

    float rmax = -3.0e38f;
    for (int n = 0; n < 64; ++n) {
        const char* cb = ebuf[n & 1];
        if (n + 1 < 64) STAGE((n + 1) & 1, n + 1);

        f32x16 acc0, acc1;
#pragma unroll
        for (int q = 0; q < 16; ++q) { acc0[q] = 0.0f; acc1[q] = 0.0f; }
#pragma unroll
        for (int kt = 0; kt < 16; ++kt) {
            bf16x8 af = *(const bf16x8*)(cb + (((abase + (unsigned)kt * 32u)) ^ sw));
            acc0 = __builtin_amdgcn_mfma_f32_32x32x16_bf16(af, bx[0][kt], acc0, 0, 0, 0);
            acc1 = __builtin_amdgcn_mfma_f32_32x32x16_bf16(af, bx[1][kt], acc1, 0, 0, 0);
        }
        // max over the 16 rows each lane holds, then merge lane-halves (xor 32)
        float m0, m1;
        {
            float a = fmaxf(fmaxf(acc0[0], acc0[1]),  fmaxf(acc0[2], acc0[3]));
            float b = fmaxf(fmaxf(acc0[4], acc0[5]),  fmaxf(acc0[6], acc0[7]));
            float c = fmaxf(fmaxf(acc0[8], acc0[9]),  fmaxf(acc0[10], acc0[11]));
            float d = fmaxf(fmaxf(acc0[12], acc0[13]),fmaxf(acc0[14], acc0[15]));
            m0 = fmaxf(fmaxf(a, b), fmaxf(c, d));
            a = fmaxf(fmaxf(acc1[0], acc1[1]),  fmaxf(acc1[2], acc1[3]));
            b = fmaxf(fmaxf(acc1[4], acc1[5]),  fmaxf(acc1[6], acc1[7]));
            c = fmaxf(fmaxf(acc1[8], acc1[9]),  fmaxf(acc1[10], acc1[11]));
            d = fmaxf(fmaxf(acc1[12], acc1[13]),fmaxf(acc1[14], acc1[15]));
            m1 = fmaxf(fmaxf(a, b), fmaxf(c, d));
        }
        m0 = fmaxf(m0, __shfl_xor(m0, 32, 64));
        m1 = fmaxf(m1, __shfl_xor(m1, 32, 64));
        const float mv = (lane < 32) ? m0 : m1;      // token = t_wave + lane
        rmax = fmaxf(rmax, mv);
        smax[(size_t)(n * 4 + csub) * NTOK + t_wave + lane] = mv;

        asm volatile("s_waitcnt vmcnt(0)");
        __syncthreads();
    }

    // per-token threshold = gmax - M2 (cross-wave merge via LDS atomicMax on ordered bits)
    if (tid < 128) tmax[tid] = 0u;
    __syncthreads();
    atomicMax(&tmax[g * 64 + lane], f_ord(rmax));
    __syncthreads();
    if (tid < 128) thr[blockIdx.x * 128 + tid] = f_unord(tmax[tid]) - M2;
}

// ===========================================================================
// k_collect: candidate cells -> compact list
__global__ __launch_bounds__(256) void k_collect(const float* __restrict__ smax,
                                                 const float* __restrict__ thr,
                                                 unsigned* __restrict__ list,
                                                 int* __restrict__ cnt,
                                                 int* __restrict__ ovf) {
    const size_t stride = (size_t)2048 * 256;
    for (size_t c = blockIdx.x * 256 + threadIdx.x; c < (size_t)256 * NTOK; c += stride) {
        const int token = (int)(c & (NTOK - 1));
        const int stile = (int)(c >> 15);
        if (smax[c] >= thr[token]) {
            const int p = atomicAdd(cnt, 1);
            if (p < CAP) list[p] = ((unsigned)token << 8) | (unsigned)stile;
            else         *ovf = 1;
        }
    }
}

// ===========================================================================
// k_exact: fp32 ref-semantics rescore of candidates (identical math to round-3 pass)
__device__ __forceinline__ float exact_score(const float* __restrict__ xr,
                                             const float* __restrict__ er,
                                             float x2t, float e2v) {
    float dot = 0.0f;
#pragma unroll 16
    for (int d = 0; d < DIM; d += 4) {
        const float4 e4 = *(const float4*)(er + d);
        const float4 x4 = *(const float4*)(xr + d);
        dot = fmaf(e4.x, x4.x, dot);
        dot = fmaf(e4.y, x4.y, dot);
        dot = fmaf(e4.z, x4.z, dot);
        dot = fmaf(e4.w, x4.w, dot);
    }
    const float A = x2t + e2v;          // fl(x2 + e2)
    return A - 2.0f * dot;              // fl(A - fl(2*dot)); 2*dot exact
}

__global__ __launch_bounds__(256) void k_exact(
        const float* __restrict__ x, const float* __restrict__ emb,
        const float* __restrict__ x2, const float* __restrict__ e2,
        const unsigned* __restrict__ list, const int* __restrict__ cnt,
        const int* __restrict__ ovf, unsigned long long* __restrict__ best) {
    const int lane = threadIdx.x & 63;
    const int half = lane >> 5, l5 = lane & 31;
    const int gw   = (blockIdx.x * 256 + threadIdx.x) >> 6;   // 2048 waves
    int n = *cnt; if (n > CAP) n = CAP;

    for (int i = gw * 2; i < n; i += 2048 * 2) {
        const int  ei    = i + half;
        const bool valid = ei < n;
        const unsigned e = list[valid ? ei : i];
        const int token  = (int)(e >> 8);
        const int v      = ((int)(e & 255u)) * 32 + l5;
        const float sc = exact_score(x + (size_t)token * DIM, emb + (size_t)v * DIM,
                                     x2[token], e2[v]);
        unsigned long long pk = ((unsigned long long)__float_as_uint(sc) << 32) | (unsigned)v;
#pragma unroll
        for (int m = 1; m < 32; m <<= 1) {
            unsigned long long o = __shfl_xor(pk, m, 64);
            if (o < pk) pk = o;
        }
        if (l5 == 0 && valid) atomicMin(&best[token], pk);
    }

    if (*ovf) {   // exhaustive safety net (never expected)
        const size_t stride = (size_t)2048 * 256;
        for (size_t c = blockIdx.x * 256 + threadIdx.x;
             c < (size_t)NTOK * VOCAB; c += stride) {
            const int token = (int)(c >> 13);
            const int v     = (int)(c & (VOCAB - 1));
            const float sc = exact_score(x + (size_t)token * DIM, emb + (size_t)v * DIM,
                                         x2[token], e2[v]);
            unsigned long long pk =
                ((unsigned long long)__float_as_uint(sc) << 32) | (unsigned)v;
            atomicMin(&best[token], pk);
        }
    }
}

__global__ __launch_bounds__(256) void k_idx(const unsigned long long* __restrict__ best,
                                             float* __restrict__ idxf) {
    const int t = blockIdx.x * 256 + threadIdx.x;
    idxf[t] = (float)(unsigned)(best[t] & 0xFFFFFFFFULL);
}

// ===========================================================================
// FALLBACK (round-3 proven path) — used when ws_size < WS_NEED
__global__ __launch_bounds__(512) void k_main_fb(
        const float* __restrict__ x, const float* __restrict__ emb,
        const float* __restrict__ x2, const float* __restrict__ e2,
        float* __restrict__ idxf) {
    __shared__ float xT[32][132];
    __shared__ float eT[32][260];
    const int tid = threadIdx.x;
    const int tx = tid & 31, ty = tid >> 5;
    const int t0 = blockIdx.x * 128;
    float x2r[8];
#pragma unroll
    for (int ii = 0; ii < 8; ++ii)
        x2r[ii] = x2[t0 + ((ii & 4) << 4) + ty * 4 + (ii & 3)];
    float tb[8]; int ti[8];
#pragma unroll
    for (int s = 0; s < 8; ++s) { tb[s] = 3.0e38f; ti[s] = 0; }
    const int xt = tid & 127, xc = tid >> 7;
    const int ev = tid & 255, ec0 = tid >> 8;
    for (int v0 = 0; v0 < VOCAB; v0 += 256) {
        float a[8][8];
#pragma unroll
        for (int i = 0; i < 8; ++i)
#pragma unroll
            for (int j = 0; j < 8; ++j) a[i][j] = 0.0f;
        for (int kk = 0; kk < DIM; kk += 32) {
            __syncthreads();
#pragma unroll
            for (int h = 0; h < 2; ++h) {
                const int kc = h * 16 + xc * 4;
                const float4 vx = *(const float4*)&x[(size_t)(t0 + xt) * DIM + kk + kc];
                xT[kc + 0][xt] = vx.x; xT[kc + 1][xt] = vx.y;
                xT[kc + 2][xt] = vx.z; xT[kc + 3][xt] = vx.w;
            }
#pragma unroll
            for (int h = 0; h < 4; ++h) {
                const int kc = (ec0 + 2 * h) * 4;
                const float4 ve = *(const float4*)&emb[(size_t)(v0 + ev) * DIM + kk + kc];
                eT[kc + 0][ev] = ve.x; eT[kc + 1][ev] = ve.y;
                eT[kc + 2][ev] = ve.z; eT[kc + 3][ev] = ve.w;
            }
            __syncthreads();
#pragma unroll 4
            for (int k = 0; k < 32; ++k) {
                float xa[8], eb[8];
                *(float4*)&xa[0] = *(const float4*)&xT[k][ty * 4];
                *(float4*)&xa[4] = *(const float4*)&xT[k][64 + ty * 4];
                *(float4*)&eb[0] = *(const float4*)&eT[k][tx * 4];
                *(float4*)&eb[4] = *(const float4*)&eT[k][128 + tx * 4];
#pragma unroll
                for (int i = 0; i < 8; ++i)
#pragma unroll
                    for (int j = 0; j < 8; ++j)
                        a[i][j] = fmaf(xa[i], eb[j], a[i][j]);
            }
        }
#pragma unroll
        for (int jj = 0; jj < 8; ++jj) {
            const int v = v0 + ((jj & 4) << 5) + tx * 4 + (jj & 3);
            const float evv = e2[v];
#pragma unroll
            for (int ii = 0; ii < 8; ++ii) {
                const float A  = x2r[ii] + evv;
                const float sc = A - 2.0f * a[ii][jj];
                if (sc < tb[ii]) { tb[ii] = sc; ti[ii] = v; }
            }
        }
    }
#pragma unroll
    for (int ii = 0; ii < 8; ++ii) {
        float b = tb[ii]; int bi = ti[ii];
#pragma unroll
        for (int m = 1; m < 32; m <<= 1) {
            const float ob = __shfl_xor(b, m, 64);
            const int   oi = __shfl_xor(bi, m, 64);
            if (ob < b || (ob == b && oi < bi)) { b = ob; bi = oi; }
        }
        if (tx == 0) {
            const int token = t0 + ((ii & 4) << 4) + ty * 4 + (ii & 3);
            idxf[token] = (float)bi;
        }
    }
}

// ===========================================================================
// gather quantised + loss reduction (shared by both paths)
__global__ __launch_bounds__(256) void k_gather(
        const float* __restrict__ x, const float* __restrict__ emb,
        const float* __restrict__ idxf, float* __restrict__ qout,
        float* __restrict__ acc) {
    const int token = blockIdx.x * 4 + (threadIdx.x >> 6);
    const int lane  = threadIdx.x & 63;
    const int v = (int)idxf[token];
    const float4 e4 = *(const float4*)&emb[(size_t)v * DIM + lane * 4];
    const float4 x4 = *(const float4*)&x[(size_t)token * DIM + lane * 4];
    *(float4*)&qout[(size_t)token * DIM + lane * 4] = e4;
    const float dx = e4.x - x4.x, dy = e4.y - x4.y, dz = e4.z - x4.z, dw = e4.w - x4.w;
    float s = dx*dx + dy*dy + dz*dz + dw*dw;
#pragma unroll
    for (int m = 1; m < 64; m <<= 1) s += __shfl_xor(s, m, 64);
    __shared__ float wsum[4];
    if (lane == 0) wsum[threadIdx.x >> 6] = s;
    __syncthreads();
    if (threadIdx.x == 0) atomicAdd(acc, wsum[0] + wsum[1] + wsum[2] + wsum[3]);
}

__global__ void k_final(const float* __restrict__ acc, float* __restrict__ out) {
    const float cb = *acc * (1.0f / 8388608.0f);
    out[LOSS_OFF] = 1.25f * cb;
    out[CB_OFF]   = cb;
}

// ===========================================================================
extern "C" void kernel_launch(void* const* d_in, const int* in_sizes, int n_in,
                              void* d_out, int out_size, void* d_ws, size_t ws_size,
                              hipStream_t stream) {
    const float* x   = (const float*)d_in[0];
    const float* emb = (const float*)d_in[1];
    float* out  = (float*)d_out;
    char*  wsB  = (char*)d_ws;
    float* wsF  = (float*)d_ws;

    float* x2   = wsF + X2_F;
    float* e2   = wsF + E2_F;
    float* acc  = wsF + ACC_F;
    int*   cnt  = (int*)wsF + CNT_I;
    int*   ovf  = (int*)wsF + OVF_I;
    unsigned long long* best = (unsigned long long*)(wsB + BEST_B);
    unsigned short*     e16  = (unsigned short*)(wsB + EMB16_B);
    float*              smax = (float*)(wsB + SMAX_B);
    float*              thrp = (float*)(wsB + THR_B);
    unsigned*           list = (unsigned*)(wsB + LIST_B);
    float* idxf = out + IDX_OFF;

    const int full = (ws_size >= (size_t)WS_NEED) ? 1 : 0;

    k_sums<<<(NTOK + VOCAB) / 16, 256, 0, stream>>>(x, emb, wsF, best, full);
    if (full) {
        k_cvt    <<<2048, 256, 0, stream>>>(emb, (unsigned*)e16);
        k_coarse <<<256, 512, 0, stream>>>(x, e16, smax, thrp);
        k_collect<<<2048, 256, 0, stream>>>(smax, thrp, list, cnt, ovf);
        k_exact  <<<512, 256, 0, stream>>>(x, emb, x2, e2, list, cnt, ovf, best);
        k_idx    <<<NTOK / 256, 256, 0, stream>>>(best, idxf);
    } else {
        k_main_fb<<<NTOK / 128, 512, 0, stream>>>(x, emb, x2, e2, idxf);
    }
    k_gather<<<NTOK / 4, 256, 0, stream>>>(x, emb, idxf, out, acc);
    k_final <<<1, 1, 0, stream>>>(acc, out);
}

// Round 5
// 551.612 us; speedup vs baseline: 3.3637x; 1.8887x over previous
//
#include <hip/hip_runtime.h>

#define VOCAB 8192
#define DIM   256
#define NTOK  32768          // 8*4096

// d_out layout (floats): quantised[8388608], loss, codebook_loss, idx[32768] (as float)
#define LOSS_OFF 8388608
#define CB_OFF   8388609
#define IDX_OFF  8388610

// ---- ws layout (bytes) ----
#define X2_F     0            // float[32768]   (f32 index)
#define E2_F     32768        // float[8192]
#define ACC_F    40960        // float
#define CNT_I    40961        // int
#define OVF_I    40962        // int
#define BEST_B   196608       // u64[32768]   -> ends 458752
#define EMB16_B  458752       // bf16[8192*256] = 4 MiB -> ends 4653056
#define SMAX_B   4718592      // float[256][32768] = 32 MiB -> ends 38273024
#define THR_B    38273024     // float[32768] (unused now, layout kept)
#define LIST_B   38404096     // u32[CAP]
#define CAP      4194304
#define WS_NEED  (LIST_B + CAP * 4)   // 55,181,312 bytes

#define M2 1.5e-4f            // dot-space rescue margin (err budget ~4e-5 practical)
#define LCAP 16000            // per-block LDS candidate cap (256*16000 < CAP)
#define NB_EXACT 2048

typedef __attribute__((ext_vector_type(8)))  short bf16x8;
typedef __attribute__((ext_vector_type(16))) float f32x16;

// ===========================================================================
// k_sums: numpy pairwise-exact x2/e2 (proven round 3) + init scalars/best
__global__ __launch_bounds__(256) void k_sums(const float* __restrict__ x,
                                              const float* __restrict__ emb,
                                              float* __restrict__ ws,
                                              unsigned long long* __restrict__ best,
                                              int full) {
    const int lane = threadIdx.x & 63;
    const int wave = threadIdx.x >> 6;
    const int row  = blockIdx.x * 16 + wave * 4 + (lane >> 4);
    const int sub  = lane & 15;
    const int k    = sub & 7;
    const int half = sub >> 3;
    const float* src = (row < NTOK ? x + (size_t)row * DIM
                                   : emb + (size_t)(row - NTOK) * DIM)
                       + half * 128 + k;
    float r;
    {
        float v0 = src[0];
        float t0 = v0 * v0;
        asm volatile("" : "+v"(t0));     // block fma contraction
        r = t0;
        for (int i = 1; i < 16; ++i) {
            float w = src[8 * i];
            float u = w * w;
            asm volatile("" : "+v"(u));
            r = r + u;
        }
    }
    float t;
    t = __shfl_xor(r, 1, 64); r = r + t;
    t = __shfl_xor(r, 2, 64); r = r + t;
    t = __shfl_xor(r, 4, 64); r = r + t;
    t = __shfl_xor(r, 8, 64); r = r + t;
    if (sub == 0) ws[row] = r;
    const int gid = blockIdx.x * 256 + threadIdx.x;
    if (gid == 0) {
        ws[ACC_F] = 0.0f;
        ((int*)ws)[CNT_I] = 0;
        ((int*)ws)[OVF_I] = 0;
    }
    if (full && gid < NTOK) best[gid] = ~0ULL;
}

// ===========================================================================
// k_cvt: emb fp32 -> bf16 (truncate; margin absorbs the bias)
__global__ __launch_bounds__(256) void k_cvt(const float* __restrict__ emb,
                                             unsigned* __restrict__ out) {
    const int i = blockIdx.x * 256 + threadIdx.x;      // 524288 threads x 4 floats
    const float4 f = *(const float4*)(emb + (size_t)i * 4);
    unsigned b0 = __float_as_uint(f.x), b1 = __float_as_uint(f.y);
    unsigned b2 = __float_as_uint(f.z), b3 = __float_as_uint(f.w);
    uint2 o;
    o.x = (b1 & 0xFFFF0000u) | (b0 >> 16);
    o.y = (b3 & 0xFFFF0000u) | (b2 >> 16);
    *(uint2*)(out + (size_t)i * 2) = o;
}

// ===========================================================================
// k_coarse: bf16 MFMA max-dot per (token, 32-code tile) + fused candidate
// collection (the block covers ALL 256 tiles of its 128 tokens, so thresholds
// and candidates are decided in-block: 1 global atomic per block, not per cell)
#define STAGE(BUFI, N) do {                                                    \
    const char* _src = (const char*)embh + ((size_t)(N) << 16);                \
    _Pragma("unroll")                                                          \
    for (int _r = 0; _r < 8; ++_r) {                                           \
        unsigned _o  = (unsigned)tid * 16u + (unsigned)_r * 8192u;             \
        unsigned _so = (_o & ~511u) | ((_o & 511u) ^ (((_o >> 9) & 7u) << 4)); \
        __builtin_amdgcn_global_load_lds(                                      \
            (const __attribute__((address_space(1))) void*)(_src + _so),       \
            (__attribute__((address_space(3))) void*)(&ebuf[(BUFI)][_o]),      \
            16, 0, 0);                                                         \
    }                                                                          \
} while (0)

__device__ __forceinline__ unsigned f_ord(float v) {
    unsigned u = __float_as_uint(v);
    return u ^ ((unsigned)((int)u >> 31) | 0x80000000u);
}
__device__ __forceinline__ float f_unord(unsigned k) {
    unsigned m = (k >> 31) ? 0x80000000u : 0xFFFFFFFFu;
    return __uint_as_float(k ^ m);
}

__global__ __launch_bounds__(512, 2) void k_coarse(
        const float* __restrict__ x, const unsigned short* __restrict__ embh,
        float* __restrict__ smax,
        unsigned* __restrict__ list, int* __restrict__ cnt,
        int* __restrict__ ovf) {
    __shared__ char ebuf[2][65536];
    __shared__ unsigned tmax[128];
    __shared__ float tthr[128];
    __shared__ unsigned gbase, bcnt;

    const int tid  = threadIdx.x;
    const int lane = tid & 63, wid = tid >> 6;
    const int g = wid & 1, csub = wid >> 1;
    const int t_wave = blockIdx.x * 128 + g * 64;

    // ---- persistent x B-frags: bx[grp][kt], token col = lane&31, k = kt*16+(lane>>5)*8+j
    bf16x8 bx[2][16];
    {
        const int tok0 = t_wave + (lane & 31);
#pragma unroll
        for (int grp = 0; grp < 2; ++grp) {
            const float* xr = x + (size_t)(tok0 + grp * 32) * DIM + (lane >> 5) * 8;
#pragma unroll
            for (int kt = 0; kt < 16; ++kt) {
                float4 f0 = *(const float4*)(xr + kt * 16);
                float4 f1 = *(const float4*)(xr + kt * 16 + 4);
                union { bf16x8 v; unsigned u[4]; } P;
                P.u[0] = (__float_as_uint(f0.y) & 0xFFFF0000u) | (__float_as_uint(f0.x) >> 16);
                P.u[1] = (__float_as_uint(f0.w) & 0xFFFF0000u) | (__float_as_uint(f0.z) >> 16);
                P.u[2] = (__float_as_uint(f1.y) & 0xFFFF0000u) | (__float_as_uint(f1.x) >> 16);
                P.u[3] = (__float_as_uint(f1.w) & 0xFFFF0000u) | (__float_as_uint(f1.z) >> 16);
                bx[grp][kt] = P.v;
            }
        }
    }

    // A-read address: row_local = csub*32 + lane&31 ; col bytes = kt*32 + (lane>>5)*16
    const unsigned rl    = (unsigned)(csub * 32 + (lane & 31));
    const unsigned abase = rl * 512u + (unsigned)((lane >> 5) * 16);
    const unsigned sw    = (rl & 7u) << 4;

    STAGE(0, 0);
    asm volatile("s_waitcnt vmcnt(0)");
    __syncthreads();

    float rmax = -3.0e38f;
    for (int n = 0; n < 64; ++n) {
        const char* cb = ebuf[n & 1];
        if (n + 1 < 64) STAGE((n + 1) & 1, n + 1);

        f32x16 acc0, acc1;
#pragma unroll
        for (int q = 0; q < 16; ++q) { acc0[q] = 0.0f; acc1[q] = 0.0f; }
#pragma unroll
        for (int kt = 0; kt < 16; ++kt) {
            bf16x8 af = *(const bf16x8*)(cb + (((abase + (unsigned)kt * 32u)) ^ sw));
            acc0 = __builtin_amdgcn_mfma_f32_32x32x16_bf16(af, bx[0][kt], acc0, 0, 0, 0);
            acc1 = __builtin_amdgcn_mfma_f32_32x32x16_bf16(af, bx[1][kt], acc1, 0, 0, 0);
        }
        // max over the 16 rows each lane holds, then merge lane-halves (xor 32)
        float m0, m1;
        {
            float a = fmaxf(fmaxf(acc0[0], acc0[1]),  fmaxf(acc0[2], acc0[3]));
            float b = fmaxf(fmaxf(acc0[4], acc0[5]),  fmaxf(acc0[6], acc0[7]));
            float c = fmaxf(fmaxf(acc0[8], acc0[9]),  fmaxf(acc0[10], acc0[11]));
            float d = fmaxf(fmaxf(acc0[12], acc0[13]),fmaxf(acc0[14], acc0[15]));
            m0 = fmaxf(fmaxf(a, b), fmaxf(c, d));
            a = fmaxf(fmaxf(acc1[0], acc1[1]),  fmaxf(acc1[2], acc1[3]));
            b = fmaxf(fmaxf(acc1[4], acc1[5]),  fmaxf(acc1[6], acc1[7]));
            c = fmaxf(fmaxf(acc1[8], acc1[9]),  fmaxf(acc1[10], acc1[11]));
            d = fmaxf(fmaxf(acc1[12], acc1[13]),fmaxf(acc1[14], acc1[15]));
            m1 = fmaxf(fmaxf(a, b), fmaxf(c, d));
        }
        m0 = fmaxf(m0, __shfl_xor(m0, 32, 64));
        m1 = fmaxf(m1, __shfl_xor(m1, 32, 64));
        const float mv = (lane < 32) ? m0 : m1;      // token = t_wave + lane
        rmax = fmaxf(rmax, mv);
        smax[(size_t)(n * 4 + csub) * NTOK + t_wave + lane] = mv;

        asm volatile("s_waitcnt vmcnt(0)");
        __syncthreads();
    }

    // ---- per-token threshold = gmax - M2 (cross-wave merge in LDS)
    unsigned* lbuf = (unsigned*)ebuf;          // main loop done: reuse as list
    if (tid < 128) tmax[tid] = 0u;
    if (tid == 0) { lbuf[0] = 0u; }
    __syncthreads();
    atomicMax(&tmax[g * 64 + lane], f_ord(rmax));
    __syncthreads();
    if (tid < 128) tthr[tid] = f_unord(tmax[tid]) - M2;
    __syncthreads();

    // ---- fused collect: re-read own smax slice (own-CU L1/L2), compact in LDS
    const int t0b = blockIdx.x * 128;
    for (int r = 0; r < 64; ++r) {
        const int cell  = r * 512 + tid;       // 0..32767
        const int stile = cell >> 7, tl = cell & 127;
        const float v = smax[(size_t)stile * NTOK + t0b + tl];
        if (v >= tthr[tl]) {
            const unsigned p = atomicAdd(&lbuf[0], 1u);
            if (p < LCAP)
                lbuf[2 + p] = ((unsigned)(t0b + tl) << 8) | (unsigned)stile;
        }
    }
    __syncthreads();
    if (tid == 0) {
        unsigned bc = lbuf[0];
        if (bc > LCAP) { bc = LCAP; *ovf = 1; }
        bcnt  = bc;
        gbase = (unsigned)atomicAdd(cnt, (int)bc);   // ONE global atomic per block
    }
    __syncthreads();
    const unsigned bc = bcnt, gb = gbase;
    for (unsigned i = tid; i < bc; i += 512) list[gb + i] = lbuf[2 + i];
}

// ===========================================================================
// k_exact: fp32 ref-semantics rescore of candidates (identical math to round 3)
__device__ __forceinline__ float exact_score(const float* __restrict__ xr,
                                             const float* __restrict__ er,
                                             float x2t, float e2v) {
    float dot = 0.0f;
#pragma unroll 16
    for (int d = 0; d < DIM; d += 4) {
        const float4 e4 = *(const float4*)(er + d);
        const float4 x4 = *(const float4*)(xr + d);
        dot = fmaf(e4.x, x4.x, dot);
        dot = fmaf(e4.y, x4.y, dot);
        dot = fmaf(e4.z, x4.z, dot);
        dot = fmaf(e4.w, x4.w, dot);
    }
    const float A = x2t + e2v;          // fl(x2 + e2)
    return A - 2.0f * dot;              // fl(A - fl(2*dot)); 2*dot exact
}

__global__ __launch_bounds__(256) void k_exact(
        const float* __restrict__ x, const float* __restrict__ emb,
        const float* __restrict__ x2, const float* __restrict__ e2,
        const unsigned* __restrict__ list, const int* __restrict__ cnt,
        const int* __restrict__ ovf, unsigned long long* __restrict__ best) {
    const int lane = threadIdx.x & 63;
    const int half = lane >> 5, l5 = lane & 31;
    const int gw   = (blockIdx.x * 256 + threadIdx.x) >> 6;   // NB_EXACT*4 waves
    int n = *cnt; if (n > CAP) n = CAP;

    for (int i = gw * 2; i < n; i += NB_EXACT * 4 * 2) {
        const int  ei    = i + half;
        const bool valid = ei < n;
        const unsigned e = list[valid ? ei : i];
        const int token  = (int)(e >> 8);
        const int v      = ((int)(e & 255u)) * 32 + l5;
        const float sc = exact_score(x + (size_t)token * DIM, emb + (size_t)v * DIM,
                                     x2[token], e2[v]);
        unsigned long long pk = ((unsigned long long)__float_as_uint(sc) << 32) | (unsigned)v;
#pragma unroll
        for (int m = 1; m < 32; m <<= 1) {
            unsigned long long o = __shfl_xor(pk, m, 64);
            if (o < pk) pk = o;
        }
        if (l5 == 0 && valid) atomicMin(&best[token], pk);
    }

    if (*ovf) {   // exhaustive safety net (never expected)
        const size_t stride = (size_t)NB_EXACT * 256;
        for (size_t c = blockIdx.x * 256 + threadIdx.x;
             c < (size_t)NTOK * VOCAB; c += stride) {
            const int token = (int)(c >> 13);
            const int v     = (int)(c & (VOCAB - 1));
            const float sc = exact_score(x + (size_t)token * DIM, emb + (size_t)v * DIM,
                                         x2[token], e2[v]);
            unsigned long long pk =
                ((unsigned long long)__float_as_uint(sc) << 32) | (unsigned)v;
            atomicMin(&best[token], pk);
        }
    }
}

__global__ __launch_bounds__(256) void k_idx(const unsigned long long* __restrict__ best,
                                             float* __restrict__ idxf) {
    const int t = blockIdx.x * 256 + threadIdx.x;
    idxf[t] = (float)(unsigned)(best[t] & 0xFFFFFFFFULL);
}

// ===========================================================================
// FALLBACK (round-3 proven path) — used when ws_size < WS_NEED
__global__ __launch_bounds__(512) void k_main_fb(
        const float* __restrict__ x, const float* __restrict__ emb,
        const float* __restrict__ x2, const float* __restrict__ e2,
        float* __restrict__ idxf) {
    __shared__ float xT[32][132];
    __shared__ float eT[32][260];
    const int tid = threadIdx.x;
    const int tx = tid & 31, ty = tid >> 5;
    const int t0 = blockIdx.x * 128;
    float x2r[8];
#pragma unroll
    for (int ii = 0; ii < 8; ++ii)
        x2r[ii] = x2[t0 + ((ii & 4) << 4) + ty * 4 + (ii & 3)];
    float tb[8]; int ti[8];
#pragma unroll
    for (int s = 0; s < 8; ++s) { tb[s] = 3.0e38f; ti[s] = 0; }
    const int xt = tid & 127, xc = tid >> 7;
    const int ev = tid & 255, ec0 = tid >> 8;
    for (int v0 = 0; v0 < VOCAB; v0 += 256) {
        float a[8][8];
#pragma unroll
        for (int i = 0; i < 8; ++i)
#pragma unroll
            for (int j = 0; j < 8; ++j) a[i][j] = 0.0f;
        for (int kk = 0; kk < DIM; kk += 32) {
            __syncthreads();
#pragma unroll
            for (int h = 0; h < 2; ++h) {
                const int kc = h * 16 + xc * 4;
                const float4 vx = *(const float4*)&x[(size_t)(t0 + xt) * DIM + kk + kc];
                xT[kc + 0][xt] = vx.x; xT[kc + 1][xt] = vx.y;
                xT[kc + 2][xt] = vx.z; xT[kc + 3][xt] = vx.w;
            }
#pragma unroll
            for (int h = 0; h < 4; ++h) {
                const int kc = (ec0 + 2 * h) * 4;
                const float4 ve = *(const float4*)&emb[(size_t)(v0 + ev) * DIM + kk + kc];
                eT[kc + 0][ev] = ve.x; eT[kc + 1][ev] = ve.y;
                eT[kc + 2][ev] = ve.z; eT[kc + 3][ev] = ve.w;
            }
            __syncthreads();
#pragma unroll 4
            for (int k = 0; k < 32; ++k) {
                float xa[8], eb[8];
                *(float4*)&xa[0] = *(const float4*)&xT[k][ty * 4];
                *(float4*)&xa[4] = *(const float4*)&xT[k][64 + ty * 4];
                *(float4*)&eb[0] = *(const float4*)&eT[k][tx * 4];
                *(float4*)&eb[4] = *(const float4*)&eT[k][128 + tx * 4];
#pragma unroll
                for (int i = 0; i < 8; ++i)
#pragma unroll
                    for (int j = 0; j < 8; ++j)
                        a[i][j] = fmaf(xa[i], eb[j], a[i][j]);
            }
        }
#pragma unroll
        for (int jj = 0; jj < 8; ++jj) {
            const int v = v0 + ((jj & 4) << 5) + tx * 4 + (jj & 3);
            const float evv = e2[v];
#pragma unroll
            for (int ii = 0; ii < 8; ++ii) {
                const float A  = x2r[ii] + evv;
                const float sc = A - 2.0f * a[ii][jj];
                if (sc < tb[ii]) { tb[ii] = sc; ti[ii] = v; }
            }
        }
    }
#pragma unroll
    for (int ii = 0; ii < 8; ++ii) {
        float b = tb[ii]; int bi = ti[ii];
#pragma unroll
        for (int m = 1; m < 32; m <<= 1) {
            const float ob = __shfl_xor(b, m, 64);
            const int   oi = __shfl_xor(bi, m, 64);
            if (ob < b || (ob == b && oi < bi)) { b = ob; bi = oi; }
        }
        if (tx == 0) {
            const int token = t0 + ((ii & 4) << 4) + ty * 4 + (ii & 3);
            idxf[token] = (float)bi;
        }
    }
}

// ===========================================================================
// gather quantised + loss reduction (shared by both paths)
__global__ __launch_bounds__(256) void k_gather(
        const float* __restrict__ x, const float* __restrict__ emb,
        const float* __restrict__ idxf, float* __restrict__ qout,
        float* __restrict__ acc) {
    const int token = blockIdx.x * 4 + (threadIdx.x >> 6);
    const int lane  = threadIdx.x & 63;
    const int v = (int)idxf[token];
    const float4 e4 = *(const float4*)&emb[(size_t)v * DIM + lane * 4];
    const float4 x4 = *(const float4*)&x[(size_t)token * DIM + lane * 4];
    *(float4*)&qout[(size_t)token * DIM + lane * 4] = e4;
    const float dx = e4.x - x4.x, dy = e4.y - x4.y, dz = e4.z - x4.z, dw = e4.w - x4.w;
    float s = dx*dx + dy*dy + dz*dz + dw*dw;
#pragma unroll
    for (int m = 1; m < 64; m <<= 1) s += __shfl_xor(s, m, 64);
    __shared__ float wsum[4];
    if (lane == 0) wsum[threadIdx.x >> 6] = s;
    __syncthreads();
    if (threadIdx.x == 0) atomicAdd(acc, wsum[0] + wsum[1] + wsum[2] + wsum[3]);
}

__global__ void k_final(const float* __restrict__ acc, float* __restrict__ out) {
    const float cb = *acc * (1.0f / 8388608.0f);
    out[LOSS_OFF] = 1.25f * cb;
    out[CB_OFF]   = cb;
}

// ===========================================================================
extern "C" void kernel_launch(void* const* d_in, const int* in_sizes, int n_in,
                              void* d_out, int out_size, void* d_ws, size_t ws_size,
                              hipStream_t stream) {
    const float* x   = (const float*)d_in[0];
    const float* emb = (const float*)d_in[1];
    float* out  = (float*)d_out;
    char*  wsB  = (char*)d_ws;
    float* wsF  = (float*)d_ws;

    float* x2   = wsF + X2_F;
    float* e2   = wsF + E2_F;
    float* acc  = wsF + ACC_F;
    int*   cnt  = (int*)wsF + CNT_I;
    int*   ovf  = (int*)wsF + OVF_I;
    unsigned long long* best = (unsigned long long*)(wsB + BEST_B);
    unsigned short*     e16  = (unsigned short*)(wsB + EMB16_B);
    float*              smax = (float*)(wsB + SMAX_B);
    unsigned*           list = (unsigned*)(wsB + LIST_B);
    float* idxf = out + IDX_OFF;

    const int full = (ws_size >= (size_t)WS_NEED) ? 1 : 0;

    k_sums<<<(NTOK + VOCAB) / 16, 256, 0, stream>>>(x, emb, wsF, best, full);
    if (full) {
        k_cvt   <<<2048, 256, 0, stream>>>(emb, (unsigned*)e16);
        k_coarse<<<256, 512, 0, stream>>>(x, e16, smax, list, cnt, ovf);
        k_exact <<<NB_EXACT, 256, 0, stream>>>(x, emb, x2, e2, list, cnt, ovf, best);
        k_idx   <<<NTOK / 256, 256, 0, stream>>>(best, idxf);
    } else {
        k_main_fb<<<NTOK / 128, 512, 0, stream>>>(x, emb, x2, e2, idxf);
    }
    k_gather<<<NTOK / 4, 256, 0, stream>>>(x, emb, idxf, out, acc);
    k_final <<<1, 1, 0, stream>>>(acc, out);
}

// Round 6
// 413.128 us; speedup vs baseline: 4.4913x; 1.3352x over previous
//
#include <hip/hip_runtime.h>

#define VOCAB 8192
#define DIM   256
#define NTOK  32768          // 8*4096

// d_out layout (floats): quantised[8388608], loss, codebook_loss, idx[32768] (as float)
#define LOSS_OFF 8388608
#define CB_OFF   8388609
#define IDX_OFF  8388610

// ---- ws layout (bytes) ----
#define X2_F     0            // float[32768]   (f32 index)
#define E2_F     32768        // float[8192]
#define ACC_F    40960        // float
#define CNT_I    40961        // int
#define OVF_I    40962        // int
#define BEST_B   196608       // u64[32768]   -> ends 458752
#define EMB16_B  458752       // bf16[8192*256] = 4 MiB -> ends 4653056
#define SMAX_B   4718592      // float[256][32768] = 32 MiB (also reused as binned list)
#define SCNT_B   38273024     // int[256]
#define SBASE_B  38274048     // int[256]
#define SCUR_B   38275072     // int[256]
#define LIST_B   38404096     // u32[CAP]
#define CAP      4194304
#define WS_NEED  (LIST_B + CAP * 4)   // 55,181,312 bytes

#define M2 1.5e-4f            // dot-space rescue margin (err budget ~6e-5 practical)
#define LCAP 16000            // per-block LDS candidate cap (256*16000 < CAP)

typedef __attribute__((ext_vector_type(8)))  short bf16x8;
typedef __attribute__((ext_vector_type(16))) float f32x16;

// ===========================================================================
// k_sums: numpy pairwise-exact x2/e2 (proven round 3) + init scalars/best/scnt
__global__ __launch_bounds__(256) void k_sums(const float* __restrict__ x,
                                              const float* __restrict__ emb,
                                              float* __restrict__ ws,
                                              unsigned long long* __restrict__ best,
                                              int* __restrict__ scnt,
                                              int full) {
    const int lane = threadIdx.x & 63;
    const int wave = threadIdx.x >> 6;
    const int row  = blockIdx.x * 16 + wave * 4 + (lane >> 4);
    const int sub  = lane & 15;
    const int k    = sub & 7;
    const int half = sub >> 3;
    const float* src = (row < NTOK ? x + (size_t)row * DIM
                                   : emb + (size_t)(row - NTOK) * DIM)
                       + half * 128 + k;
    float r;
    {
        float v0 = src[0];
        float t0 = v0 * v0;
        asm volatile("" : "+v"(t0));     // block fma contraction
        r = t0;
        for (int i = 1; i < 16; ++i) {
            float w = src[8 * i];
            float u = w * w;
            asm volatile("" : "+v"(u));
            r = r + u;
        }
    }
    float t;
    t = __shfl_xor(r, 1, 64); r = r + t;
    t = __shfl_xor(r, 2, 64); r = r + t;
    t = __shfl_xor(r, 4, 64); r = r + t;
    t = __shfl_xor(r, 8, 64); r = r + t;
    if (sub == 0) ws[row] = r;
    const int gid = blockIdx.x * 256 + threadIdx.x;
    if (gid == 0) {
        ws[ACC_F] = 0.0f;
        ((int*)ws)[CNT_I] = 0;
        ((int*)ws)[OVF_I] = 0;
    }
    if (full) {
        if (gid < NTOK) best[gid] = ~0ULL;
        if (gid < 256)  scnt[gid] = 0;
    }
}

// ===========================================================================
// k_cvt: emb fp32 -> bf16 (truncate; margin absorbs the bias)
__global__ __launch_bounds__(256) void k_cvt(const float* __restrict__ emb,
                                             unsigned* __restrict__ out) {
    const int i = blockIdx.x * 256 + threadIdx.x;      // 524288 threads x 4 floats
    const float4 f = *(const float4*)(emb + (size_t)i * 4);
    unsigned b0 = __float_as_uint(f.x), b1 = __float_as_uint(f.y);
    unsigned b2 = __float_as_uint(f.z), b3 = __float_as_uint(f.w);
    uint2 o;
    o.x = (b1 & 0xFFFF0000u) | (b0 >> 16);
    o.y = (b3 & 0xFFFF0000u) | (b2 >> 16);
    *(uint2*)(out + (size_t)i * 2) = o;
}

// ===========================================================================
// k_coarse: bf16 MFMA max-dot per (token, 32-code tile) + fused candidate
// collection (1 global atomic per block)
#define STAGE(BUFI, N) do {                                                    \
    const char* _src = (const char*)embh + ((size_t)(N) << 16);                \
    _Pragma("unroll")                                                          \
    for (int _r = 0; _r < 8; ++_r) {                                           \
        unsigned _o  = (unsigned)tid * 16u + (unsigned)_r * 8192u;             \
        unsigned _so = (_o & ~511u) | ((_o & 511u) ^ (((_o >> 9) & 7u) << 4)); \
        __builtin_amdgcn_global_load_lds(                                      \
            (const __attribute__((address_space(1))) void*)(_src + _so),       \
            (__attribute__((address_space(3))) void*)(&ebuf[(BUFI)][_o]),      \
            16, 0, 0);                                                         \
    }                                                                          \
} while (0)

__device__ __forceinline__ unsigned f_ord(float v) {
    unsigned u = __float_as_uint(v);
    return u ^ ((unsigned)((int)u >> 31) | 0x80000000u);
}
__device__ __forceinline__ float f_unord(unsigned k) {
    unsigned m = (k >> 31) ? 0x80000000u : 0xFFFFFFFFu;
    return __uint_as_float(k ^ m);
}

__global__ __launch_bounds__(512, 2) void k_coarse(
        const float* __restrict__ x, const unsigned short* __restrict__ embh,
        float* __restrict__ smax,
        unsigned* __restrict__ list, int* __restrict__ cnt,
        int* __restrict__ ovf) {
    __shared__ char ebuf[2][65536];
    __shared__ unsigned tmax[128];
    __shared__ float tthr[128];
    __shared__ unsigned gbase, bcnt;

    const int tid  = threadIdx.x;
    const int lane = tid & 63, wid = tid >> 6;
    const int g = wid & 1, csub = wid >> 1;
    const int t_wave = blockIdx.x * 128 + g * 64;

    // ---- persistent x B-frags: bx[grp][kt], token col = lane&31, k = kt*16+(lane>>5)*8+j
    bf16x8 bx[2][16];
    {
        const int tok0 = t_wave + (lane & 31);
#pragma unroll
        for (int grp = 0; grp < 2; ++grp) {
            const float* xr = x + (size_t)(tok0 + grp * 32) * DIM + (lane >> 5) * 8;
#pragma unroll
            for (int kt = 0; kt < 16; ++kt) {
                float4 f0 = *(const float4*)(xr + kt * 16);
                float4 f1 = *(const float4*)(xr + kt * 16 + 4);
                union { bf16x8 v; unsigned u[4]; } P;
                P.u[0] = (__float_as_uint(f0.y) & 0xFFFF0000u) | (__float_as_uint(f0.x) >> 16);
                P.u[1] = (__float_as_uint(f0.w) & 0xFFFF0000u) | (__float_as_uint(f0.z) >> 16);
                P.u[2] = (__float_as_uint(f1.y) & 0xFFFF0000u) | (__float_as_uint(f1.x) >> 16);
                P.u[3] = (__float_as_uint(f1.w) & 0xFFFF0000u) | (__float_as_uint(f1.z) >> 16);
                bx[grp][kt] = P.v;
            }
        }
    }

    const unsigned rl    = (unsigned)(csub * 32 + (lane & 31));
    const unsigned abase = rl * 512u + (unsigned)((lane >> 5) * 16);
    const unsigned sw    = (rl & 7u) << 4;

    STAGE(0, 0);
    asm volatile("s_waitcnt vmcnt(0)");
    __syncthreads();

    float rmax = -3.0e38f;
    for (int n = 0; n < 64; ++n) {
        const char* cb = ebuf[n & 1];
        if (n + 1 < 64) STAGE((n + 1) & 1, n + 1);

        f32x16 acc0, acc1;
#pragma unroll
        for (int q = 0; q < 16; ++q) { acc0[q] = 0.0f; acc1[q] = 0.0f; }
#pragma unroll
        for (int kt = 0; kt < 16; ++kt) {
            bf16x8 af = *(const bf16x8*)(cb + (((abase + (unsigned)kt * 32u)) ^ sw));
            acc0 = __builtin_amdgcn_mfma_f32_32x32x16_bf16(af, bx[0][kt], acc0, 0, 0, 0);
            acc1 = __builtin_amdgcn_mfma_f32_32x32x16_bf16(af, bx[1][kt], acc1, 0, 0, 0);
        }
        float m0, m1;
        {
            float a = fmaxf(fmaxf(acc0[0], acc0[1]),  fmaxf(acc0[2], acc0[3]));
            float b = fmaxf(fmaxf(acc0[4], acc0[5]),  fmaxf(acc0[6], acc0[7]));
            float c = fmaxf(fmaxf(acc0[8], acc0[9]),  fmaxf(acc0[10], acc0[11]));
            float d = fmaxf(fmaxf(acc0[12], acc0[13]),fmaxf(acc0[14], acc0[15]));
            m0 = fmaxf(fmaxf(a, b), fmaxf(c, d));
            a = fmaxf(fmaxf(acc1[0], acc1[1]),  fmaxf(acc1[2], acc1[3]));
            b = fmaxf(fmaxf(acc1[4], acc1[5]),  fmaxf(acc1[6], acc1[7]));
            c = fmaxf(fmaxf(acc1[8], acc1[9]),  fmaxf(acc1[10], acc1[11]));
            d = fmaxf(fmaxf(acc1[12], acc1[13]),fmaxf(acc1[14], acc1[15]));
            m1 = fmaxf(fmaxf(a, b), fmaxf(c, d));
        }
        m0 = fmaxf(m0, __shfl_xor(m0, 32, 64));
        m1 = fmaxf(m1, __shfl_xor(m1, 32, 64));
        const float mv = (lane < 32) ? m0 : m1;      // token = t_wave + lane
        rmax = fmaxf(rmax, mv);
        smax[(size_t)(n * 4 + csub) * NTOK + t_wave + lane] = mv;

        asm volatile("s_waitcnt vmcnt(0)");
        __syncthreads();
    }

    // ---- per-token threshold = gmax - M2 (cross-wave merge in LDS)
    unsigned* lbuf = (unsigned*)ebuf;          // main loop done: reuse as list
    if (tid < 128) tmax[tid] = 0u;
    if (tid == 0) { lbuf[0] = 0u; }
    __syncthreads();
    atomicMax(&tmax[g * 64 + lane], f_ord(rmax));
    __syncthreads();
    if (tid < 128) tthr[tid] = f_unord(tmax[tid]) - M2;
    __syncthreads();

    // ---- fused collect: re-read own smax slice, compact in LDS
    const int t0b = blockIdx.x * 128;
    for (int r = 0; r < 64; ++r) {
        const int cell  = r * 512 + tid;       // 0..32767
        const int stile = cell >> 7, tl = cell & 127;
        const float v = smax[(size_t)stile * NTOK + t0b + tl];
        if (v >= tthr[tl]) {
            const unsigned p = atomicAdd(&lbuf[0], 1u);
            if (p < LCAP)
                lbuf[2 + p] = ((unsigned)(t0b + tl) << 8) | (unsigned)stile;
        }
    }
    __syncthreads();
    if (tid == 0) {
        unsigned bc = lbuf[0];
        if (bc > LCAP) { bc = LCAP; *ovf = 1; }
        bcnt  = bc;
        gbase = (unsigned)atomicAdd(cnt, (int)bc);   // ONE global atomic per block
    }
    __syncthreads();
    const unsigned bc = bcnt, gb = gbase;
    for (unsigned i = tid; i < bc; i += 512) list[gb + i] = lbuf[2 + i];
}

// ===========================================================================
// Binning: count per stile -> scan -> scatter into per-stile buckets
__global__ __launch_bounds__(256) void k_bincount(const unsigned* __restrict__ list,
                                                  const int* __restrict__ cnt,
                                                  int* __restrict__ scnt) {
    __shared__ int lc[256];
    lc[threadIdx.x] = 0;
    __syncthreads();
    int n = *cnt; if (n > CAP) n = CAP;
    for (int i = blockIdx.x * 256 + threadIdx.x; i < n; i += 64 * 256)
        atomicAdd(&lc[list[i] & 255u], 1);
    __syncthreads();
    if (lc[threadIdx.x]) atomicAdd(&scnt[threadIdx.x], lc[threadIdx.x]);
}

__global__ __launch_bounds__(256) void k_scan(const int* __restrict__ scnt,
                                              int* __restrict__ sbase,
                                              int* __restrict__ scur) {
    __shared__ int a[256], b[256];
    const int t = threadIdx.x;
    a[t] = scnt[t];
    __syncthreads();
    int* src = a; int* dst = b;
    for (int off = 1; off < 256; off <<= 1) {
        dst[t] = src[t] + ((t >= off) ? src[t - off] : 0);
        __syncthreads();
        int* tp = src; src = dst; dst = tp;
    }
    const int excl = src[t] - scnt[t];
    sbase[t] = excl;
    scur[t]  = excl;
}

__global__ __launch_bounds__(256) void k_scatter(const unsigned* __restrict__ list,
                                                 const int* __restrict__ cnt,
                                                 int* __restrict__ scur,
                                                 unsigned* __restrict__ binned) {
    int n = *cnt; if (n > CAP) n = CAP;
    for (int i = blockIdx.x * 256 + threadIdx.x; i < n; i += 64 * 256) {
        const unsigned e = list[i];
        const int p = atomicAdd(&scur[e & 255u], 1);
        binned[p] = e;
    }
}

// ===========================================================================
// k_exact2: per-stile buckets, emb tile in LDS, ref-bit-identical fp32 score
__device__ __forceinline__ float exact_score(const float* __restrict__ xr,
                                             const float* __restrict__ er,
                                             float x2t, float e2v) {
    float dot = 0.0f;
#pragma unroll 16
    for (int d = 0; d < DIM; d += 4) {
        const float4 e4 = *(const float4*)(er + d);
        const float4 x4 = *(const float4*)(xr + d);
        dot = fmaf(e4.x, x4.x, dot);
        dot = fmaf(e4.y, x4.y, dot);
        dot = fmaf(e4.z, x4.z, dot);
        dot = fmaf(e4.w, x4.w, dot);
    }
    const float A = x2t + e2v;          // fl(x2 + e2)
    return A - 2.0f * dot;              // fl(A - fl(2*dot)); 2*dot exact
}

__global__ __launch_bounds__(256) void k_exact2(
        const float* __restrict__ x, const float* __restrict__ emb,
        const float* __restrict__ x2, const float* __restrict__ e2,
        const unsigned* __restrict__ binned, const int* __restrict__ sbase,
        const int* __restrict__ scnt, const int* __restrict__ ovf,
        unsigned long long* __restrict__ best) {
    __shared__ float elds[32][257];
    __shared__ float e2s[32];
    const int s = blockIdx.x >> 3, sub = blockIdx.x & 7;
    {   // stage this stile's 32 emb rows (fp32) into LDS
        const int r = threadIdx.x >> 3, c0 = (threadIdx.x & 7) * 32;
        const float* er = emb + (size_t)(s * 32 + r) * DIM + c0;
#pragma unroll
        for (int q = 0; q < 8; ++q) {
            const float4 f = *(const float4*)(er + q * 4);
            elds[r][c0 + q * 4 + 0] = f.x; elds[r][c0 + q * 4 + 1] = f.y;
            elds[r][c0 + q * 4 + 2] = f.z; elds[r][c0 + q * 4 + 3] = f.w;
        }
        if (threadIdx.x < 32) e2s[threadIdx.x] = e2[s * 32 + threadIdx.x];
    }
    __syncthreads();

    const int lane = threadIdx.x & 63, wave = threadIdx.x >> 6;
    const int l5 = lane & 31, half = lane >> 5;
    const int base = sbase[s], count = scnt[s];
    const float e2v = e2s[l5];

    for (int k = (sub * 4 + wave) * 2 + half; k < count; k += 64) {
        const unsigned e = binned[base + k];
        const int token  = (int)(e >> 8);
        const float* xr  = x + (size_t)token * DIM;
        const float x2t  = x2[token];
        // sequential fmaf chain, d ascending, x/y/z/w order == proven ref semantics
        float dot = 0.0f;
#pragma unroll 16
        for (int d = 0; d < DIM; d += 4) {
            const float4 x4 = *(const float4*)(xr + d);
            dot = fmaf(elds[l5][d + 0], x4.x, dot);
            dot = fmaf(elds[l5][d + 1], x4.y, dot);
            dot = fmaf(elds[l5][d + 2], x4.z, dot);
            dot = fmaf(elds[l5][d + 3], x4.w, dot);
        }
        const float A  = x2t + e2v;
        const float sc = A - 2.0f * dot;
        unsigned long long pk =
            ((unsigned long long)__float_as_uint(sc) << 32) | (unsigned)(s * 32 + l5);
#pragma unroll
        for (int m = 1; m < 32; m <<= 1) {   // stays within the 32-lane half
            unsigned long long o = __shfl_xor(pk, m, 64);
            if (o < pk) pk = o;
        }
        if (l5 == 0) atomicMin(&best[token], pk);
    }

    if (*ovf) {   // exhaustive safety net (never expected)
        const size_t stride = (size_t)2048 * 256;
        for (size_t c = blockIdx.x * 256 + threadIdx.x;
             c < (size_t)NTOK * VOCAB; c += stride) {
            const int token = (int)(c >> 13);
            const int v     = (int)(c & (VOCAB - 1));
            const float sc = exact_score(x + (size_t)token * DIM, emb + (size_t)v * DIM,
                                         x2[token], e2[v]);
            unsigned long long pk =
                ((unsigned long long)__float_as_uint(sc) << 32) | (unsigned)v;
            atomicMin(&best[token], pk);
        }
    }
}

__global__ __launch_bounds__(256) void k_idx(const unsigned long long* __restrict__ best,
                                             float* __restrict__ idxf) {
    const int t = blockIdx.x * 256 + threadIdx.x;
    idxf[t] = (float)(unsigned)(best[t] & 0xFFFFFFFFULL);
}

// ===========================================================================
// FALLBACK (round-3 proven path) — used when ws_size < WS_NEED
__global__ __launch_bounds__(512) void k_main_fb(
        const float* __restrict__ x, const float* __restrict__ emb,
        const float* __restrict__ x2, const float* __restrict__ e2,
        float* __restrict__ idxf) {
    __shared__ float xT[32][132];
    __shared__ float eT[32][260];
    const int tid = threadIdx.x;
    const int tx = tid & 31, ty = tid >> 5;
    const int t0 = blockIdx.x * 128;
    float x2r[8];
#pragma unroll
    for (int ii = 0; ii < 8; ++ii)
        x2r[ii] = x2[t0 + ((ii & 4) << 4) + ty * 4 + (ii & 3)];
    float tb[8]; int ti[8];
#pragma unroll
    for (int s = 0; s < 8; ++s) { tb[s] = 3.0e38f; ti[s] = 0; }
    const int xt = tid & 127, xc = tid >> 7;
    const int ev = tid & 255, ec0 = tid >> 8;
    for (int v0 = 0; v0 < VOCAB; v0 += 256) {
        float a[8][8];
#pragma unroll
        for (int i = 0; i < 8; ++i)
#pragma unroll
            for (int j = 0; j < 8; ++j) a[i][j] = 0.0f;
        for (int kk = 0; kk < DIM; kk += 32) {
            __syncthreads();
#pragma unroll
            for (int h = 0; h < 2; ++h) {
                const int kc = h * 16 + xc * 4;
                const float4 vx = *(const float4*)&x[(size_t)(t0 + xt) * DIM + kk + kc];
                xT[kc + 0][xt] = vx.x; xT[kc + 1][xt] = vx.y;
                xT[kc + 2][xt] = vx.z; xT[kc + 3][xt] = vx.w;
            }
#pragma unroll
            for (int h = 0; h < 4; ++h) {
                const int kc = (ec0 + 2 * h) * 4;
                const float4 ve = *(const float4*)&emb[(size_t)(v0 + ev) * DIM + kk + kc];
                eT[kc + 0][ev] = ve.x; eT[kc + 1][ev] = ve.y;
                eT[kc + 2][ev] = ve.z; eT[kc + 3][ev] = ve.w;
            }
            __syncthreads();
#pragma unroll 4
            for (int k = 0; k < 32; ++k) {
                float xa[8], eb[8];
                *(float4*)&xa[0] = *(const float4*)&xT[k][ty * 4];
                *(float4*)&xa[4] = *(const float4*)&xT[k][64 + ty * 4];
                *(float4*)&eb[0] = *(const float4*)&eT[k][tx * 4];
                *(float4*)&eb[4] = *(const float4*)&eT[k][128 + tx * 4];
#pragma unroll
                for (int i = 0; i < 8; ++i)
#pragma unroll
                    for (int j = 0; j < 8; ++j)
                        a[i][j] = fmaf(xa[i], eb[j], a[i][j]);
            }
        }
#pragma unroll
        for (int jj = 0; jj < 8; ++jj) {
            const int v = v0 + ((jj & 4) << 5) + tx * 4 + (jj & 3);
            const float evv = e2[v];
#pragma unroll
            for (int ii = 0; ii < 8; ++ii) {
                const float A  = x2r[ii] + evv;
                const float sc = A - 2.0f * a[ii][jj];
                if (sc < tb[ii]) { tb[ii] = sc; ti[ii] = v; }
            }
        }
    }
#pragma unroll
    for (int ii = 0; ii < 8; ++ii) {
        float b = tb[ii]; int bi = ti[ii];
#pragma unroll
        for (int m = 1; m < 32; m <<= 1) {
            const float ob = __shfl_xor(b, m, 64);
            const int   oi = __shfl_xor(bi, m, 64);
            if (ob < b || (ob == b && oi < bi)) { b = ob; bi = oi; }
        }
        if (tx == 0) {
            const int token = t0 + ((ii & 4) << 4) + ty * 4 + (ii & 3);
            idxf[token] = (float)bi;
        }
    }
}

// ===========================================================================
// gather quantised + loss reduction (shared by both paths)
__global__ __launch_bounds__(256) void k_gather(
        const float* __restrict__ x, const float* __restrict__ emb,
        const float* __restrict__ idxf, float* __restrict__ qout,
        float* __restrict__ acc) {
    const int token = blockIdx.x * 4 + (threadIdx.x >> 6);
    const int lane  = threadIdx.x & 63;
    const int v = (int)idxf[token];
    const float4 e4 = *(const float4*)&emb[(size_t)v * DIM + lane * 4];
    const float4 x4 = *(const float4*)&x[(size_t)token * DIM + lane * 4];
    *(float4*)&qout[(size_t)token * DIM + lane * 4] = e4;
    const float dx = e4.x - x4.x, dy = e4.y - x4.y, dz = e4.z - x4.z, dw = e4.w - x4.w;
    float s = dx*dx + dy*dy + dz*dz + dw*dw;
#pragma unroll
    for (int m = 1; m < 64; m <<= 1) s += __shfl_xor(s, m, 64);
    __shared__ float wsum[4];
    if (lane == 0) wsum[threadIdx.x >> 6] = s;
    __syncthreads();
    if (threadIdx.x == 0) atomicAdd(acc, wsum[0] + wsum[1] + wsum[2] + wsum[3]);
}

__global__ void k_final(const float* __restrict__ acc, float* __restrict__ out) {
    const float cb = *acc * (1.0f / 8388608.0f);
    out[LOSS_OFF] = 1.25f * cb;
    out[CB_OFF]   = cb;
}

// ===========================================================================
extern "C" void kernel_launch(void* const* d_in, const int* in_sizes, int n_in,
                              void* d_out, int out_size, void* d_ws, size_t ws_size,
                              hipStream_t stream) {
    const float* x   = (const float*)d_in[0];
    const float* emb = (const float*)d_in[1];
    float* out  = (float*)d_out;
    char*  wsB  = (char*)d_ws;
    float* wsF  = (float*)d_ws;

    float* x2   = wsF + X2_F;
    float* e2   = wsF + E2_F;
    float* acc  = wsF + ACC_F;
    int*   cnt  = (int*)wsF + CNT_I;
    int*   ovf  = (int*)wsF + OVF_I;
    unsigned long long* best = (unsigned long long*)(wsB + BEST_B);
    unsigned short*     e16  = (unsigned short*)(wsB + EMB16_B);
    float*              smax = (float*)(wsB + SMAX_B);
    unsigned*           binned = (unsigned*)(wsB + SMAX_B);   // reuse after collect
    int*                scnt  = (int*)(wsB + SCNT_B);
    int*                sbase = (int*)(wsB + SBASE_B);
    int*                scur  = (int*)(wsB + SCUR_B);
    unsigned*           list  = (unsigned*)(wsB + LIST_B);
    float* idxf = out + IDX_OFF;

    const int full = (ws_size >= (size_t)WS_NEED) ? 1 : 0;

    k_sums<<<(NTOK + VOCAB) / 16, 256, 0, stream>>>(x, emb, wsF, best, scnt, full);
    if (full) {
        k_cvt     <<<2048, 256, 0, stream>>>(emb, (unsigned*)e16);
        k_coarse  <<<256, 512, 0, stream>>>(x, e16, smax, list, cnt, ovf);
        k_bincount<<<64, 256, 0, stream>>>(list, cnt, scnt);
        k_scan    <<<1, 256, 0, stream>>>(scnt, sbase, scur);
        k_scatter <<<64, 256, 0, stream>>>(list, cnt, scur, binned);
        k_exact2  <<<2048, 256, 0, stream>>>(x, emb, x2, e2, binned, sbase, scnt, ovf, best);
        k_idx     <<<NTOK / 256, 256, 0, stream>>>(best, idxf);
    } else {
        k_main_fb<<<NTOK / 128, 512, 0, stream>>>(x, emb, x2, e2, idxf);
    }
    k_gather<<<NTOK / 4, 256, 0, stream>>>(x, emb, idxf, out, acc);
    k_final <<<1, 1, 0, stream>>>(acc, out);
}

// Round 7
// 409.622 us; speedup vs baseline: 4.5297x; 1.0086x over previous
//
#include <hip/hip_runtime.h>

#define VOCAB 8192
#define DIM   256
#define NTOK  32768          // 8*4096

// d_out layout (floats): quantised[8388608], loss, codebook_loss, idx[32768] (as float)
#define LOSS_OFF 8388608
#define CB_OFF   8388609
#define IDX_OFF  8388610

// ---- ws layout (bytes) ----
#define X2_F     0            // float[32768]   (f32 index)
#define E2_F     32768        // float[8192]
#define ACC_F    40960        // float
#define CNT_I    40961        // int
#define OVF_I    40962        // int
#define BEST_B   196608       // u64[32768]   -> ends 458752
#define EMB16_B  458752       // bf16[8192*256] = 4 MiB -> ends 4653056
#define SMAX_B   4718592      // float[256][32768] = 32 MiB (also reused as binned list)
#define SCNT_B   38273024     // int[256]
#define SBASE_B  38274048     // int[256]
#define SCUR_B   38275072     // int[256]
#define LIST_B   38404096     // u32[CAP]
#define CAP      4194304
#define WS_NEED  (LIST_B + CAP * 4)   // 55,181,312 bytes

#define M2 1.5e-4f            // dot-space rescue margin (err budget ~6e-5 practical)
#define LCAP 16000            // per-block LDS candidate cap (256*16000 < CAP)

typedef __attribute__((ext_vector_type(8)))  short bf16x8;
typedef __attribute__((ext_vector_type(16))) float f32x16;

// ===========================================================================
// k_sums: numpy pairwise-exact x2/e2 (proven round 3) + init scalars/best/scnt
__global__ __launch_bounds__(256) void k_sums(const float* __restrict__ x,
                                              const float* __restrict__ emb,
                                              float* __restrict__ ws,
                                              unsigned long long* __restrict__ best,
                                              int* __restrict__ scnt,
                                              int full) {
    const int lane = threadIdx.x & 63;
    const int wave = threadIdx.x >> 6;
    const int row  = blockIdx.x * 16 + wave * 4 + (lane >> 4);
    const int sub  = lane & 15;
    const int k    = sub & 7;
    const int half = sub >> 3;
    const float* src = (row < NTOK ? x + (size_t)row * DIM
                                   : emb + (size_t)(row - NTOK) * DIM)
                       + half * 128 + k;
    float r;
    {
        float v0 = src[0];
        float t0 = v0 * v0;
        asm volatile("" : "+v"(t0));     // block fma contraction
        r = t0;
        for (int i = 1; i < 16; ++i) {
            float w = src[8 * i];
            float u = w * w;
            asm volatile("" : "+v"(u));
            r = r + u;
        }
    }
    float t;
    t = __shfl_xor(r, 1, 64); r = r + t;
    t = __shfl_xor(r, 2, 64); r = r + t;
    t = __shfl_xor(r, 4, 64); r = r + t;
    t = __shfl_xor(r, 8, 64); r = r + t;
    if (sub == 0) ws[row] = r;
    const int gid = blockIdx.x * 256 + threadIdx.x;
    if (gid == 0) {
        ws[ACC_F] = 0.0f;
        ((int*)ws)[CNT_I] = 0;
        ((int*)ws)[OVF_I] = 0;
    }
    if (full) {
        if (gid < NTOK) best[gid] = ~0ULL;
        if (gid < 256)  scnt[gid] = 0;
    }
}

// ===========================================================================
// k_cvt: emb fp32 -> bf16 (truncate; margin absorbs the bias)
__global__ __launch_bounds__(256) void k_cvt(const float* __restrict__ emb,
                                             unsigned* __restrict__ out) {
    const int i = blockIdx.x * 256 + threadIdx.x;      // 524288 threads x 4 floats
    const float4 f = *(const float4*)(emb + (size_t)i * 4);
    unsigned b0 = __float_as_uint(f.x), b1 = __float_as_uint(f.y);
    unsigned b2 = __float_as_uint(f.z), b3 = __float_as_uint(f.w);
    uint2 o;
    o.x = (b1 & 0xFFFF0000u) | (b0 >> 16);
    o.y = (b3 & 0xFFFF0000u) | (b2 >> 16);
    *(uint2*)(out + (size_t)i * 2) = o;
}

// ===========================================================================
// k_coarse: bf16 MFMA max-dot per (token, 32-code tile) + fused candidate
// collection. 5-bit XOR swizzle (pre-swizzled global source, linear LDS dest,
// same XOR on read) -> conflict-free ds_read_b128 (2 lanes/slot = wave64 min).
#define STAGE(BUFI, N) do {                                                     \
    const char* _src = (const char*)embh + ((size_t)(N) << 16);                 \
    _Pragma("unroll")                                                           \
    for (int _r = 0; _r < 8; ++_r) {                                            \
        unsigned _o  = (unsigned)tid * 16u + (unsigned)_r * 8192u;              \
        unsigned _so = (_o & ~511u) | ((_o & 511u) ^ (((_o >> 9) & 31u) << 4)); \
        __builtin_amdgcn_global_load_lds(                                       \
            (const __attribute__((address_space(1))) void*)(_src + _so),        \
            (__attribute__((address_space(3))) void*)(&ebuf[(BUFI)][_o]),       \
            16, 0, 0);                                                          \
    }                                                                           \
} while (0)

__device__ __forceinline__ unsigned f_ord(float v) {
    unsigned u = __float_as_uint(v);
    return u ^ ((unsigned)((int)u >> 31) | 0x80000000u);
}
__device__ __forceinline__ float f_unord(unsigned k) {
    unsigned m = (k >> 31) ? 0x80000000u : 0xFFFFFFFFu;
    return __uint_as_float(k ^ m);
}

__global__ __launch_bounds__(512, 2) void k_coarse(
        const float* __restrict__ x, const unsigned short* __restrict__ embh,
        float* __restrict__ smax,
        unsigned* __restrict__ list, int* __restrict__ cnt,
        int* __restrict__ ovf) {
    __shared__ char ebuf[2][65536];
    __shared__ unsigned tmax[128];
    __shared__ float tthr[128];
    __shared__ unsigned gbase, bcnt;

    const int tid  = threadIdx.x;
    const int lane = tid & 63, wid = tid >> 6;
    const int g = wid & 1, csub = wid >> 1;
    const int t_wave = blockIdx.x * 128 + g * 64;

    // ---- persistent x B-frags: bx[grp][kt], token col = lane&31, k = kt*16+(lane>>5)*8+j
    bf16x8 bx[2][16];
    {
        const int tok0 = t_wave + (lane & 31);
#pragma unroll
        for (int grp = 0; grp < 2; ++grp) {
            const float* xr = x + (size_t)(tok0 + grp * 32) * DIM + (lane >> 5) * 8;
#pragma unroll
            for (int kt = 0; kt < 16; ++kt) {
                float4 f0 = *(const float4*)(xr + kt * 16);
                float4 f1 = *(const float4*)(xr + kt * 16 + 4);
                union { bf16x8 v; unsigned u[4]; } P;
                P.u[0] = (__float_as_uint(f0.y) & 0xFFFF0000u) | (__float_as_uint(f0.x) >> 16);
                P.u[1] = (__float_as_uint(f0.w) & 0xFFFF0000u) | (__float_as_uint(f0.z) >> 16);
                P.u[2] = (__float_as_uint(f1.y) & 0xFFFF0000u) | (__float_as_uint(f1.x) >> 16);
                P.u[3] = (__float_as_uint(f1.w) & 0xFFFF0000u) | (__float_as_uint(f1.z) >> 16);
                bx[grp][kt] = P.v;
            }
        }
    }

    // A-read: row rl = csub*32 + lane&31, col bytes = kt*32 + (lane>>5)*16
    const unsigned rl    = (unsigned)(csub * 32 + (lane & 31));
    const unsigned abase = rl * 512u + (unsigned)((lane >> 5) * 16);
    const unsigned sw    = (rl & 31u) << 4;     // 5-bit XOR: 32 distinct slots

    STAGE(0, 0);
    asm volatile("s_waitcnt vmcnt(0)");
    __syncthreads();

    float rmax = -3.0e38f;
    for (int n = 0; n < 64; ++n) {
        const char* cb = ebuf[n & 1];
        if (n + 1 < 64) STAGE((n + 1) & 1, n + 1);

        f32x16 acc0, acc1;
#pragma unroll
        for (int q = 0; q < 16; ++q) { acc0[q] = 0.0f; acc1[q] = 0.0f; }
#pragma unroll
        for (int h2 = 0; h2 < 2; ++h2) {
            // batch 8 ds_read_b128 into regs, then a 16-MFMA cluster:
            // LDS latency paid twice per chunk instead of 16x
            bf16x8 af[8];
#pragma unroll
            for (int j = 0; j < 8; ++j)
                af[j] = *(const bf16x8*)(cb + ((abase + (unsigned)(h2 * 8 + j) * 32u) ^ sw));
            __builtin_amdgcn_s_setprio(1);
#pragma unroll
            for (int j = 0; j < 8; ++j) {
                acc0 = __builtin_amdgcn_mfma_f32_32x32x16_bf16(af[j], bx[0][h2 * 8 + j], acc0, 0, 0, 0);
                acc1 = __builtin_amdgcn_mfma_f32_32x32x16_bf16(af[j], bx[1][h2 * 8 + j], acc1, 0, 0, 0);
            }
            __builtin_amdgcn_s_setprio(0);
        }
        float m0, m1;
        {
            float a = fmaxf(fmaxf(acc0[0], acc0[1]),  fmaxf(acc0[2], acc0[3]));
            float b = fmaxf(fmaxf(acc0[4], acc0[5]),  fmaxf(acc0[6], acc0[7]));
            float c = fmaxf(fmaxf(acc0[8], acc0[9]),  fmaxf(acc0[10], acc0[11]));
            float d = fmaxf(fmaxf(acc0[12], acc0[13]),fmaxf(acc0[14], acc0[15]));
            m0 = fmaxf(fmaxf(a, b), fmaxf(c, d));
            a = fmaxf(fmaxf(acc1[0], acc1[1]),  fmaxf(acc1[2], acc1[3]));
            b = fmaxf(fmaxf(acc1[4], acc1[5]),  fmaxf(acc1[6], acc1[7]));
            c = fmaxf(fmaxf(acc1[8], acc1[9]),  fmaxf(acc1[10], acc1[11]));
            d = fmaxf(fmaxf(acc1[12], acc1[13]),fmaxf(acc1[14], acc1[15]));
            m1 = fmaxf(fmaxf(a, b), fmaxf(c, d));
        }
        m0 = fmaxf(m0, __shfl_xor(m0, 32, 64));
        m1 = fmaxf(m1, __shfl_xor(m1, 32, 64));
        const float mv = (lane < 32) ? m0 : m1;      // token = t_wave + lane
        rmax = fmaxf(rmax, mv);
        smax[(size_t)(n * 4 + csub) * NTOK + t_wave + lane] = mv;

        asm volatile("s_waitcnt vmcnt(0)");
        __syncthreads();
    }

    // ---- per-token threshold = gmax - M2 (cross-wave merge in LDS)
    unsigned* lbuf = (unsigned*)ebuf;          // main loop done: reuse as list
    if (tid < 128) tmax[tid] = 0u;
    if (tid == 0) { lbuf[0] = 0u; }
    __syncthreads();
    atomicMax(&tmax[g * 64 + lane], f_ord(rmax));
    __syncthreads();
    if (tid < 128) tthr[tid] = f_unord(tmax[tid]) - M2;
    __syncthreads();

    // ---- fused collect: re-read own smax slice, compact in LDS
    const int t0b = blockIdx.x * 128;
    for (int r = 0; r < 64; ++r) {
        const int cell  = r * 512 + tid;       // 0..32767
        const int stile = cell >> 7, tl = cell & 127;
        const float v = smax[(size_t)stile * NTOK + t0b + tl];
        if (v >= tthr[tl]) {
            const unsigned p = atomicAdd(&lbuf[0], 1u);
            if (p < LCAP)
                lbuf[2 + p] = ((unsigned)(t0b + tl) << 8) | (unsigned)stile;
        }
    }
    __syncthreads();
    if (tid == 0) {
        unsigned bc = lbuf[0];
        if (bc > LCAP) { bc = LCAP; *ovf = 1; }
        bcnt  = bc;
        gbase = (unsigned)atomicAdd(cnt, (int)bc);   // ONE global atomic per block
    }
    __syncthreads();
    const unsigned bc = bcnt, gb = gbase;
    for (unsigned i = tid; i < bc; i += 512) list[gb + i] = lbuf[2 + i];
}

// ===========================================================================
// Binning: count per stile -> scan -> scatter into per-stile buckets
__global__ __launch_bounds__(256) void k_bincount(const unsigned* __restrict__ list,
                                                  const int* __restrict__ cnt,
                                                  int* __restrict__ scnt) {
    __shared__ int lc[256];
    lc[threadIdx.x] = 0;
    __syncthreads();
    int n = *cnt; if (n > CAP) n = CAP;
    for (int i = blockIdx.x * 256 + threadIdx.x; i < n; i += 64 * 256)
        atomicAdd(&lc[list[i] & 255u], 1);
    __syncthreads();
    if (lc[threadIdx.x]) atomicAdd(&scnt[threadIdx.x], lc[threadIdx.x]);
}

__global__ __launch_bounds__(256) void k_scan(const int* __restrict__ scnt,
                                              int* __restrict__ sbase,
                                              int* __restrict__ scur) {
    __shared__ int a[256], b[256];
    const int t = threadIdx.x;
    a[t] = scnt[t];
    __syncthreads();
    int* src = a; int* dst = b;
    for (int off = 1; off < 256; off <<= 1) {
        dst[t] = src[t] + ((t >= off) ? src[t - off] : 0);
        __syncthreads();
        int* tp = src; src = dst; dst = tp;
    }
    const int excl = src[t] - scnt[t];
    sbase[t] = excl;
    scur[t]  = excl;
}

__global__ __launch_bounds__(256) void k_scatter(const unsigned* __restrict__ list,
                                                 const int* __restrict__ cnt,
                                                 int* __restrict__ scur,
                                                 unsigned* __restrict__ binned) {
    int n = *cnt; if (n > CAP) n = CAP;
    for (int i = blockIdx.x * 256 + threadIdx.x; i < n; i += 64 * 256) {
        const unsigned e = list[i];
        const int p = atomicAdd(&scur[e & 255u], 1);
        binned[p] = e;
    }
}

// ===========================================================================
// k_exact2: per-stile buckets, emb tile in LDS, ref-bit-identical fp32 score
__device__ __forceinline__ float exact_score(const float* __restrict__ xr,
                                             const float* __restrict__ er,
                                             float x2t, float e2v) {
    float dot = 0.0f;
#pragma unroll 16
    for (int d = 0; d < DIM; d += 4) {
        const float4 e4 = *(const float4*)(er + d);
        const float4 x4 = *(const float4*)(xr + d);
        dot = fmaf(e4.x, x4.x, dot);
        dot = fmaf(e4.y, x4.y, dot);
        dot = fmaf(e4.z, x4.z, dot);
        dot = fmaf(e4.w, x4.w, dot);
    }
    const float A = x2t + e2v;          // fl(x2 + e2)
    return A - 2.0f * dot;              // fl(A - fl(2*dot)); 2*dot exact
}

__global__ __launch_bounds__(256) void k_exact2(
        const float* __restrict__ x, const float* __restrict__ emb,
        const float* __restrict__ x2, const float* __restrict__ e2,
        const unsigned* __restrict__ binned, const int* __restrict__ sbase,
        const int* __restrict__ scnt, const int* __restrict__ ovf,
        unsigned long long* __restrict__ best) {
    __shared__ float elds[32][257];
    __shared__ float e2s[32];
    const int s = blockIdx.x >> 3, sub = blockIdx.x & 7;
    {   // stage this stile's 32 emb rows (fp32) into LDS
        const int r = threadIdx.x >> 3, c0 = (threadIdx.x & 7) * 32;
        const float* er = emb + (size_t)(s * 32 + r) * DIM + c0;
#pragma unroll
        for (int q = 0; q < 8; ++q) {
            const float4 f = *(const float4*)(er + q * 4);
            elds[r][c0 + q * 4 + 0] = f.x; elds[r][c0 + q * 4 + 1] = f.y;
            elds[r][c0 + q * 4 + 2] = f.z; elds[r][c0 + q * 4 + 3] = f.w;
        }
        if (threadIdx.x < 32) e2s[threadIdx.x] = e2[s * 32 + threadIdx.x];
    }
    __syncthreads();

    const int lane = threadIdx.x & 63, wave = threadIdx.x >> 6;
    const int l5 = lane & 31, half = lane >> 5;
    const int base = sbase[s], count = scnt[s];
    const float e2v = e2s[l5];

    for (int k = (sub * 4 + wave) * 2 + half; k < count; k += 64) {
        const unsigned e = binned[base + k];
        const int token  = (int)(e >> 8);
        const float* xr  = x + (size_t)token * DIM;
        const float x2t  = x2[token];
        // sequential fmaf chain, d ascending, x/y/z/w order == proven ref semantics
        float dot = 0.0f;
#pragma unroll 16
        for (int d = 0; d < DIM; d += 4) {
            const float4 x4 = *(const float4*)(xr + d);
            dot = fmaf(elds[l5][d + 0], x4.x, dot);
            dot = fmaf(elds[l5][d + 1], x4.y, dot);
            dot = fmaf(elds[l5][d + 2], x4.z, dot);
            dot = fmaf(elds[l5][d + 3], x4.w, dot);
        }
        const float A  = x2t + e2v;
        const float sc = A - 2.0f * dot;
        unsigned long long pk =
            ((unsigned long long)__float_as_uint(sc) << 32) | (unsigned)(s * 32 + l5);
#pragma unroll
        for (int m = 1; m < 32; m <<= 1) {   // stays within the 32-lane half
            unsigned long long o = __shfl_xor(pk, m, 64);
            if (o < pk) pk = o;
        }
        if (l5 == 0) atomicMin(&best[token], pk);
    }

    if (*ovf) {   // exhaustive safety net (never expected)
        const size_t stride = (size_t)2048 * 256;
        for (size_t c = blockIdx.x * 256 + threadIdx.x;
             c < (size_t)NTOK * VOCAB; c += stride) {
            const int token = (int)(c >> 13);
            const int v     = (int)(c & (VOCAB - 1));
            const float sc = exact_score(x + (size_t)token * DIM, emb + (size_t)v * DIM,
                                         x2[token], e2[v]);
            unsigned long long pk =
                ((unsigned long long)__float_as_uint(sc) << 32) | (unsigned)v;
            atomicMin(&best[token], pk);
        }
    }
}

__global__ __launch_bounds__(256) void k_idx(const unsigned long long* __restrict__ best,
                                             float* __restrict__ idxf) {
    const int t = blockIdx.x * 256 + threadIdx.x;
    idxf[t] = (float)(unsigned)(best[t] & 0xFFFFFFFFULL);
}

// ===========================================================================
// FALLBACK (round-3 proven path) — used when ws_size < WS_NEED
__global__ __launch_bounds__(512) void k_main_fb(
        const float* __restrict__ x, const float* __restrict__ emb,
        const float* __restrict__ x2, const float* __restrict__ e2,
        float* __restrict__ idxf) {
    __shared__ float xT[32][132];
    __shared__ float eT[32][260];
    const int tid = threadIdx.x;
    const int tx = tid & 31, ty = tid >> 5;
    const int t0 = blockIdx.x * 128;
    float x2r[8];
#pragma unroll
    for (int ii = 0; ii < 8; ++ii)
        x2r[ii] = x2[t0 + ((ii & 4) << 4) + ty * 4 + (ii & 3)];
    float tb[8]; int ti[8];
#pragma unroll
    for (int s = 0; s < 8; ++s) { tb[s] = 3.0e38f; ti[s] = 0; }
    const int xt = tid & 127, xc = tid >> 7;
    const int ev = tid & 255, ec0 = tid >> 8;
    for (int v0 = 0; v0 < VOCAB; v0 += 256) {
        float a[8][8];
#pragma unroll
        for (int i = 0; i < 8; ++i)
#pragma unroll
            for (int j = 0; j < 8; ++j) a[i][j] = 0.0f;
        for (int kk = 0; kk < DIM; kk += 32) {
            __syncthreads();
#pragma unroll
            for (int h = 0; h < 2; ++h) {
                const int kc = h * 16 + xc * 4;
                const float4 vx = *(const float4*)&x[(size_t)(t0 + xt) * DIM + kk + kc];
                xT[kc + 0][xt] = vx.x; xT[kc + 1][xt] = vx.y;
                xT[kc + 2][xt] = vx.z; xT[kc + 3][xt] = vx.w;
            }
#pragma unroll
            for (int h = 0; h < 4; ++h) {
                const int kc = (ec0 + 2 * h) * 4;
                const float4 ve = *(const float4*)&emb[(size_t)(v0 + ev) * DIM + kk + kc];
                eT[kc + 0][ev] = ve.x; eT[kc + 1][ev] = ve.y;
                eT[kc + 2][ev] = ve.z; eT[kc + 3][ev] = ve.w;
            }
            __syncthreads();
#pragma unroll 4
            for (int k = 0; k < 32; ++k) {
                float xa[8], eb[8];
                *(float4*)&xa[0] = *(const float4*)&xT[k][ty * 4];
                *(float4*)&xa[4] = *(const float4*)&xT[k][64 + ty * 4];
                *(float4*)&eb[0] = *(const float4*)&eT[k][tx * 4];
                *(float4*)&eb[4] = *(const float4*)&eT[k][128 + tx * 4];
#pragma unroll
                for (int i = 0; i < 8; ++i)
#pragma unroll
                    for (int j = 0; j < 8; ++j)
                        a[i][j] = fmaf(xa[i], eb[j], a[i][j]);
            }
        }
#pragma unroll
        for (int jj = 0; jj < 8; ++jj) {
            const int v = v0 + ((jj & 4) << 5) + tx * 4 + (jj & 3);
            const float evv = e2[v];
#pragma unroll
            for (int ii = 0; ii < 8; ++ii) {
                const float A  = x2r[ii] + evv;
                const float sc = A - 2.0f * a[ii][jj];
                if (sc < tb[ii]) { tb[ii] = sc; ti[ii] = v; }
            }
        }
    }
#pragma unroll
    for (int ii = 0; ii < 8; ++ii) {
        float b = tb[ii]; int bi = ti[ii];
#pragma unroll
        for (int m = 1; m < 32; m <<= 1) {
            const float ob = __shfl_xor(b, m, 64);
            const int   oi = __shfl_xor(bi, m, 64);
            if (ob < b || (ob == b && oi < bi)) { b = ob; bi = oi; }
        }
        if (tx == 0) {
            const int token = t0 + ((ii & 4) << 4) + ty * 4 + (ii & 3);
            idxf[token] = (float)bi;
        }
    }
}

// ===========================================================================
// gather quantised + loss reduction (shared by both paths)
__global__ __launch_bounds__(256) void k_gather(
        const float* __restrict__ x, const float* __restrict__ emb,
        const float* __restrict__ idxf, float* __restrict__ qout,
        float* __restrict__ acc) {
    const int token = blockIdx.x * 4 + (threadIdx.x >> 6);
    const int lane  = threadIdx.x & 63;
    const int v = (int)idxf[token];
    const float4 e4 = *(const float4*)&emb[(size_t)v * DIM + lane * 4];
    const float4 x4 = *(const float4*)&x[(size_t)token * DIM + lane * 4];
    *(float4*)&qout[(size_t)token * DIM + lane * 4] = e4;
    const float dx = e4.x - x4.x, dy = e4.y - x4.y, dz = e4.z - x4.z, dw = e4.w - x4.w;
    float s = dx*dx + dy*dy + dz*dz + dw*dw;
#pragma unroll
    for (int m = 1; m < 64; m <<= 1) s += __shfl_xor(s, m, 64);
    __shared__ float wsum[4];
    if (lane == 0) wsum[threadIdx.x >> 6] = s;
    __syncthreads();
    if (threadIdx.x == 0) atomicAdd(acc, wsum[0] + wsum[1] + wsum[2] + wsum[3]);
}

__global__ void k_final(const float* __restrict__ acc, float* __restrict__ out) {
    const float cb = *acc * (1.0f / 8388608.0f);
    out[LOSS_OFF] = 1.25f * cb;
    out[CB_OFF]   = cb;
}

// ===========================================================================
extern "C" void kernel_launch(void* const* d_in, const int* in_sizes, int n_in,
                              void* d_out, int out_size, void* d_ws, size_t ws_size,
                              hipStream_t stream) {
    const float* x   = (const float*)d_in[0];
    const float* emb = (const float*)d_in[1];
    float* out  = (float*)d_out;
    char*  wsB  = (char*)d_ws;
    float* wsF  = (float*)d_ws;

    float* x2   = wsF + X2_F;
    float* e2   = wsF + E2_F;
    float* acc  = wsF + ACC_F;
    int*   cnt  = (int*)wsF + CNT_I;
    int*   ovf  = (int*)wsF + OVF_I;
    unsigned long long* best = (unsigned long long*)(wsB + BEST_B);
    unsigned short*     e16  = (unsigned short*)(wsB + EMB16_B);
    float*              smax = (float*)(wsB + SMAX_B);
    unsigned*           binned = (unsigned*)(wsB + SMAX_B);   // reuse after collect
    int*                scnt  = (int*)(wsB + SCNT_B);
    int*                sbase = (int*)(wsB + SBASE_B);
    int*                scur  = (int*)(wsB + SCUR_B);
    unsigned*           list  = (unsigned*)(wsB + LIST_B);
    float* idxf = out + IDX_OFF;

    const int full = (ws_size >= (size_t)WS_NEED) ? 1 : 0;

    k_sums<<<(NTOK + VOCAB) / 16, 256, 0, stream>>>(x, emb, wsF, best, scnt, full);
    if (full) {
        k_cvt     <<<2048, 256, 0, stream>>>(emb, (unsigned*)e16);
        k_coarse  <<<256, 512, 0, stream>>>(x, e16, smax, list, cnt, ovf);
        k_bincount<<<64, 256, 0, stream>>>(list, cnt, scnt);
        k_scan    <<<1, 256, 0, stream>>>(scnt, sbase, scur);
        k_scatter <<<64, 256, 0, stream>>>(list, cnt, scur, binned);
        k_exact2  <<<2048, 256, 0, stream>>>(x, emb, x2, e2, binned, sbase, scnt, ovf, best);
        k_idx     <<<NTOK / 256, 256, 0, stream>>>(best, idxf);
    } else {
        k_main_fb<<<NTOK / 128, 512, 0, stream>>>(x, emb, x2, e2, idxf);
    }
    k_gather<<<NTOK / 4, 256, 0, stream>>>(x, emb, idxf, out, acc);
    k_final <<<1, 1, 0, stream>>>(acc, out);
}

// Round 8
// 405.638 us; speedup vs baseline: 4.5742x; 1.0098x over previous
//
#include <hip/hip_runtime.h>

#define VOCAB 8192
#define DIM   256
#define NTOK  32768          // 8*4096

// d_out layout (floats): quantised[8388608], loss, codebook_loss, idx[32768] (as float)
#define LOSS_OFF 8388608
#define CB_OFF   8388609
#define IDX_OFF  8388610

// ---- ws layout (bytes) ----
#define X2_F     0            // float[32768]   (f32 index)
#define E2_F     32768        // float[8192]
#define ACC_F    40960        // float
#define CNT_I    40961        // int
#define OVF_I    40962        // int
#define BEST_B   196608       // u64[32768]   -> ends 458752
#define EMB16_B  458752       // bf16[8192*256] = 4 MiB -> ends 4653056
#define SMAX_B   4718592      // float[256][32768] = 32 MiB (also reused as binned list)
#define SCNT_B   38273024     // int[256]
#define SBASE_B  38274048     // int[256]
#define SCUR_B   38275072     // int[256]
#define LIST_B   38404096     // u32[CAP]
#define CAP      4194304
#define WS_NEED  (LIST_B + CAP * 4)   // 55,181,312 bytes

#define M2 1.5e-4f            // dot-space rescue margin (err budget ~6e-5 practical)
#define LCAP 16000            // per-block LDS candidate cap (256*16000 < CAP)

typedef __attribute__((ext_vector_type(8)))  short bf16x8;
typedef __attribute__((ext_vector_type(16))) float f32x16;

// ===========================================================================
// k_sums: numpy pairwise-exact x2/e2 (proven round 3) + init scalars/best/scnt
__global__ __launch_bounds__(256) void k_sums(const float* __restrict__ x,
                                              const float* __restrict__ emb,
                                              float* __restrict__ ws,
                                              unsigned long long* __restrict__ best,
                                              int* __restrict__ scnt,
                                              int full) {
    const int lane = threadIdx.x & 63;
    const int wave = threadIdx.x >> 6;
    const int row  = blockIdx.x * 16 + wave * 4 + (lane >> 4);
    const int sub  = lane & 15;
    const int k    = sub & 7;
    const int half = sub >> 3;
    const float* src = (row < NTOK ? x + (size_t)row * DIM
                                   : emb + (size_t)(row - NTOK) * DIM)
                       + half * 128 + k;
    float r;
    {
        float v0 = src[0];
        float t0 = v0 * v0;
        asm volatile("" : "+v"(t0));     // block fma contraction
        r = t0;
        for (int i = 1; i < 16; ++i) {
            float w = src[8 * i];
            float u = w * w;
            asm volatile("" : "+v"(u));
            r = r + u;
        }
    }
    float t;
    t = __shfl_xor(r, 1, 64); r = r + t;
    t = __shfl_xor(r, 2, 64); r = r + t;
    t = __shfl_xor(r, 4, 64); r = r + t;
    t = __shfl_xor(r, 8, 64); r = r + t;
    if (sub == 0) ws[row] = r;
    const int gid = blockIdx.x * 256 + threadIdx.x;
    if (gid == 0) {
        ws[ACC_F] = 0.0f;
        ((int*)ws)[CNT_I] = 0;
        ((int*)ws)[OVF_I] = 0;
    }
    if (full) {
        if (gid < NTOK) best[gid] = ~0ULL;
        if (gid < 256)  scnt[gid] = 0;
    }
}

// ===========================================================================
// k_cvt: emb fp32 -> bf16 (truncate; margin absorbs the bias)
__global__ __launch_bounds__(256) void k_cvt(const float* __restrict__ emb,
                                             unsigned* __restrict__ out) {
    const int i = blockIdx.x * 256 + threadIdx.x;      // 524288 threads x 4 floats
    const float4 f = *(const float4*)(emb + (size_t)i * 4);
    unsigned b0 = __float_as_uint(f.x), b1 = __float_as_uint(f.y);
    unsigned b2 = __float_as_uint(f.z), b3 = __float_as_uint(f.w);
    uint2 o;
    o.x = (b1 & 0xFFFF0000u) | (b0 >> 16);
    o.y = (b3 & 0xFFFF0000u) | (b2 >> 16);
    *(uint2*)(out + (size_t)i * 2) = o;
}

// ===========================================================================
// k_coarse: bf16 MFMA max-dot per (token, 32-code tile) + fused candidate
// collection. 5-bit XOR swizzle (pre-swizzled global source, linear LDS dest,
// same XOR on read) -> conflict-free ds_read_b128 (2 lanes/slot = wave64 min).
// T3/T4 pipeline: counted vmcnt(8) (never 0 in the main loop) + raw barriers —
// stage(n+1) loads stay in flight across compute(n).
#define STAGE(BUFI, N) do {                                                     \
    const char* _src = (const char*)embh + ((size_t)(N) << 16);                 \
    _Pragma("unroll")                                                           \
    for (int _r = 0; _r < 8; ++_r) {                                            \
        unsigned _o  = (unsigned)tid * 16u + (unsigned)_r * 8192u;              \
        unsigned _so = (_o & ~511u) | ((_o & 511u) ^ (((_o >> 9) & 31u) << 4)); \
        __builtin_amdgcn_global_load_lds(                                       \
            (const __attribute__((address_space(1))) void*)(_src + _so),        \
            (__attribute__((address_space(3))) void*)(&ebuf[(BUFI)][_o]),       \
            16, 0, 0);                                                          \
    }                                                                           \
} while (0)

__device__ __forceinline__ unsigned f_ord(float v) {
    unsigned u = __float_as_uint(v);
    return u ^ ((unsigned)((int)u >> 31) | 0x80000000u);
}
__device__ __forceinline__ float f_unord(unsigned k) {
    unsigned m = (k >> 31) ? 0x80000000u : 0xFFFFFFFFu;
    return __uint_as_float(k ^ m);
}

__global__ __launch_bounds__(512, 2) void k_coarse(
        const float* __restrict__ x, const unsigned short* __restrict__ embh,
        float* __restrict__ smax,
        unsigned* __restrict__ list, int* __restrict__ cnt,
        int* __restrict__ ovf) {
    __shared__ char ebuf[2][65536];
    __shared__ unsigned tmax[128];
    __shared__ float tthr[128];
    __shared__ unsigned gbase, bcnt;

    const int tid  = threadIdx.x;
    const int lane = tid & 63, wid = tid >> 6;
    const int g = wid & 1, csub = wid >> 1;
    const int t_wave = blockIdx.x * 128 + g * 64;

    // ---- persistent x B-frags: bx[grp][kt], token col = lane&31, k = kt*16+(lane>>5)*8+j
    bf16x8 bx[2][16];
    {
        const int tok0 = t_wave + (lane & 31);
#pragma unroll
        for (int grp = 0; grp < 2; ++grp) {
            const float* xr = x + (size_t)(tok0 + grp * 32) * DIM + (lane >> 5) * 8;
#pragma unroll
            for (int kt = 0; kt < 16; ++kt) {
                float4 f0 = *(const float4*)(xr + kt * 16);
                float4 f1 = *(const float4*)(xr + kt * 16 + 4);
                union { bf16x8 v; unsigned u[4]; } P;
                P.u[0] = (__float_as_uint(f0.y) & 0xFFFF0000u) | (__float_as_uint(f0.x) >> 16);
                P.u[1] = (__float_as_uint(f0.w) & 0xFFFF0000u) | (__float_as_uint(f0.z) >> 16);
                P.u[2] = (__float_as_uint(f1.y) & 0xFFFF0000u) | (__float_as_uint(f1.x) >> 16);
                P.u[3] = (__float_as_uint(f1.w) & 0xFFFF0000u) | (__float_as_uint(f1.z) >> 16);
                bx[grp][kt] = P.v;
            }
        }
    }

    // A-read: row rl = csub*32 + lane&31, col bytes = kt*32 + (lane>>5)*16
    const unsigned rl    = (unsigned)(csub * 32 + (lane & 31));
    const unsigned abase = rl * 512u + (unsigned)((lane >> 5) * 16);
    const unsigned sw    = (rl & 31u) << 4;     // 5-bit XOR: 32 distinct slots

    STAGE(0, 0);

    float rmax = -3.0e38f;
    for (int n = 0; n < 64; ++n) {
        const char* cb = ebuf[n & 1];
        if (n + 1 < 64) {
            STAGE((n + 1) & 1, n + 1);
            // counted wait: oldest 8 (= stage n) must land; stage n+1 stays in flight
            asm volatile("s_waitcnt vmcnt(8)" ::: "memory");
        } else {
            asm volatile("s_waitcnt vmcnt(0)" ::: "memory");
        }
        __builtin_amdgcn_s_barrier();       // all waves: buf[n&1] fully staged
        asm volatile("" ::: "memory");

        f32x16 acc0, acc1;
#pragma unroll
        for (int q = 0; q < 16; ++q) { acc0[q] = 0.0f; acc1[q] = 0.0f; }
#pragma unroll
        for (int h2 = 0; h2 < 2; ++h2) {
            // batch 8 ds_read_b128 into regs, then a 16-MFMA cluster
            bf16x8 af[8];
#pragma unroll
            for (int j = 0; j < 8; ++j)
                af[j] = *(const bf16x8*)(cb + ((abase + (unsigned)(h2 * 8 + j) * 32u) ^ sw));
            __builtin_amdgcn_s_setprio(1);
#pragma unroll
            for (int j = 0; j < 8; ++j) {
                acc0 = __builtin_amdgcn_mfma_f32_32x32x16_bf16(af[j], bx[0][h2 * 8 + j], acc0, 0, 0, 0);
                acc1 = __builtin_amdgcn_mfma_f32_32x32x16_bf16(af[j], bx[1][h2 * 8 + j], acc1, 0, 0, 0);
            }
            __builtin_amdgcn_s_setprio(0);
        }
        float m0, m1;
        {
            float a = fmaxf(fmaxf(acc0[0], acc0[1]),  fmaxf(acc0[2], acc0[3]));
            float b = fmaxf(fmaxf(acc0[4], acc0[5]),  fmaxf(acc0[6], acc0[7]));
            float c = fmaxf(fmaxf(acc0[8], acc0[9]),  fmaxf(acc0[10], acc0[11]));
            float d = fmaxf(fmaxf(acc0[12], acc0[13]),fmaxf(acc0[14], acc0[15]));
            m0 = fmaxf(fmaxf(a, b), fmaxf(c, d));
            a = fmaxf(fmaxf(acc1[0], acc1[1]),  fmaxf(acc1[2], acc1[3]));
            b = fmaxf(fmaxf(acc1[4], acc1[5]),  fmaxf(acc1[6], acc1[7]));
            c = fmaxf(fmaxf(acc1[8], acc1[9]),  fmaxf(acc1[10], acc1[11]));
            d = fmaxf(fmaxf(acc1[12], acc1[13]),fmaxf(acc1[14], acc1[15]));
            m1 = fmaxf(fmaxf(a, b), fmaxf(c, d));
        }
        m0 = fmaxf(m0, __shfl_xor(m0, 32, 64));
        m1 = fmaxf(m1, __shfl_xor(m1, 32, 64));
        const float mv = (lane < 32) ? m0 : m1;      // token = t_wave + lane
        rmax = fmaxf(rmax, mv);
        smax[(size_t)(n * 4 + csub) * NTOK + t_wave + lane] = mv;

        asm volatile("" ::: "memory");
        __builtin_amdgcn_s_barrier();       // all waves done reading buf[n&1]
    }

    // ---- per-token threshold = gmax - M2 (cross-wave merge in LDS)
    unsigned* lbuf = (unsigned*)ebuf;          // main loop done: reuse as list
    if (tid < 128) tmax[tid] = 0u;
    if (tid == 0) { lbuf[0] = 0u; }
    __syncthreads();
    atomicMax(&tmax[g * 64 + lane], f_ord(rmax));
    __syncthreads();
    if (tid < 128) tthr[tid] = f_unord(tmax[tid]) - M2;
    __syncthreads();

    // ---- fused collect: re-read own smax slice, compact in LDS
    const int t0b = blockIdx.x * 128;
    for (int r = 0; r < 64; ++r) {
        const int cell  = r * 512 + tid;       // 0..32767
        const int stile = cell >> 7, tl = cell & 127;
        const float v = smax[(size_t)stile * NTOK + t0b + tl];
        if (v >= tthr[tl]) {
            const unsigned p = atomicAdd(&lbuf[0], 1u);
            if (p < LCAP)
                lbuf[2 + p] = ((unsigned)(t0b + tl) << 8) | (unsigned)stile;
        }
    }
    __syncthreads();
    if (tid == 0) {
        unsigned bc = lbuf[0];
        if (bc > LCAP) { bc = LCAP; *ovf = 1; }
        bcnt  = bc;
        gbase = (unsigned)atomicAdd(cnt, (int)bc);   // ONE global atomic per block
    }
    __syncthreads();
    const unsigned bc = bcnt, gb = gbase;
    for (unsigned i = tid; i < bc; i += 512) list[gb + i] = lbuf[2 + i];
}

// ===========================================================================
// Binning: count per stile -> scan -> scatter into per-stile buckets
__global__ __launch_bounds__(256) void k_bincount(const unsigned* __restrict__ list,
                                                  const int* __restrict__ cnt,
                                                  int* __restrict__ scnt) {
    __shared__ int lc[256];
    lc[threadIdx.x] = 0;
    __syncthreads();
    int n = *cnt; if (n > CAP) n = CAP;
    for (int i = blockIdx.x * 256 + threadIdx.x; i < n; i += 64 * 256)
        atomicAdd(&lc[list[i] & 255u], 1);
    __syncthreads();
    if (lc[threadIdx.x]) atomicAdd(&scnt[threadIdx.x], lc[threadIdx.x]);
}

__global__ __launch_bounds__(256) void k_scan(const int* __restrict__ scnt,
                                              int* __restrict__ sbase,
                                              int* __restrict__ scur) {
    __shared__ int a[256], b[256];
    const int t = threadIdx.x;
    a[t] = scnt[t];
    __syncthreads();
    int* src = a; int* dst = b;
    for (int off = 1; off < 256; off <<= 1) {
        dst[t] = src[t] + ((t >= off) ? src[t - off] : 0);
        __syncthreads();
        int* tp = src; src = dst; dst = tp;
    }
    const int excl = src[t] - scnt[t];
    sbase[t] = excl;
    scur[t]  = excl;
}

__global__ __launch_bounds__(256) void k_scatter(const unsigned* __restrict__ list,
                                                 const int* __restrict__ cnt,
                                                 int* __restrict__ scur,
                                                 unsigned* __restrict__ binned) {
    int n = *cnt; if (n > CAP) n = CAP;
    for (int i = blockIdx.x * 256 + threadIdx.x; i < n; i += 64 * 256) {
        const unsigned e = list[i];
        const int p = atomicAdd(&scur[e & 255u], 1);
        binned[p] = e;
    }
}

// ===========================================================================
// k_exact2: per-stile buckets, emb tile in LDS, ref-bit-identical fp32 score
__device__ __forceinline__ float exact_score(const float* __restrict__ xr,
                                             const float* __restrict__ er,
                                             float x2t, float e2v) {
    float dot = 0.0f;
#pragma unroll 16
    for (int d = 0; d < DIM; d += 4) {
        const float4 e4 = *(const float4*)(er + d);
        const float4 x4 = *(const float4*)(xr + d);
        dot = fmaf(e4.x, x4.x, dot);
        dot = fmaf(e4.y, x4.y, dot);
        dot = fmaf(e4.z, x4.z, dot);
        dot = fmaf(e4.w, x4.w, dot);
    }
    const float A = x2t + e2v;          // fl(x2 + e2)
    return A - 2.0f * dot;              // fl(A - fl(2*dot)); 2*dot exact
}

__global__ __launch_bounds__(256) void k_exact2(
        const float* __restrict__ x, const float* __restrict__ emb,
        const float* __restrict__ x2, const float* __restrict__ e2,
        const unsigned* __restrict__ binned, const int* __restrict__ sbase,
        const int* __restrict__ scnt, const int* __restrict__ ovf,
        unsigned long long* __restrict__ best) {
    __shared__ float elds[32][257];
    __shared__ float e2s[32];
    const int s = blockIdx.x >> 3, sub = blockIdx.x & 7;
    {   // stage this stile's 32 emb rows (fp32) into LDS
        const int r = threadIdx.x >> 3, c0 = (threadIdx.x & 7) * 32;
        const float* er = emb + (size_t)(s * 32 + r) * DIM + c0;
#pragma unroll
        for (int q = 0; q < 8; ++q) {
            const float4 f = *(const float4*)(er + q * 4);
            elds[r][c0 + q * 4 + 0] = f.x; elds[r][c0 + q * 4 + 1] = f.y;
            elds[r][c0 + q * 4 + 2] = f.z; elds[r][c0 + q * 4 + 3] = f.w;
        }
        if (threadIdx.x < 32) e2s[threadIdx.x] = e2[s * 32 + threadIdx.x];
    }
    __syncthreads();

    const int lane = threadIdx.x & 63, wave = threadIdx.x >> 6;
    const int l5 = lane & 31, half = lane >> 5;
    const int base = sbase[s], count = scnt[s];
    const float e2v = e2s[l5];

    for (int k = (sub * 4 + wave) * 2 + half; k < count; k += 64) {
        const unsigned e = binned[base + k];
        const int token  = (int)(e >> 8);
        const float* xr  = x + (size_t)token * DIM;
        const float x2t  = x2[token];
        // sequential fmaf chain, d ascending, x/y/z/w order == proven ref semantics
        float dot = 0.0f;
#pragma unroll 16
        for (int d = 0; d < DIM; d += 4) {
            const float4 x4 = *(const float4*)(xr + d);
            dot = fmaf(elds[l5][d + 0], x4.x, dot);
            dot = fmaf(elds[l5][d + 1], x4.y, dot);
            dot = fmaf(elds[l5][d + 2], x4.z, dot);
            dot = fmaf(elds[l5][d + 3], x4.w, dot);
        }
        const float A  = x2t + e2v;
        const float sc = A - 2.0f * dot;
        unsigned long long pk =
            ((unsigned long long)__float_as_uint(sc) << 32) | (unsigned)(s * 32 + l5);
#pragma unroll
        for (int m = 1; m < 32; m <<= 1) {   // stays within the 32-lane half
            unsigned long long o = __shfl_xor(pk, m, 64);
            if (o < pk) pk = o;
        }
        if (l5 == 0) atomicMin(&best[token], pk);
    }

    if (*ovf) {   // exhaustive safety net (never expected)
        const size_t stride = (size_t)2048 * 256;
        for (size_t c = blockIdx.x * 256 + threadIdx.x;
             c < (size_t)NTOK * VOCAB; c += stride) {
            const int token = (int)(c >> 13);
            const int v     = (int)(c & (VOCAB - 1));
            const float sc = exact_score(x + (size_t)token * DIM, emb + (size_t)v * DIM,
                                         x2[token], e2[v]);
            unsigned long long pk =
                ((unsigned long long)__float_as_uint(sc) << 32) | (unsigned)v;
            atomicMin(&best[token], pk);
        }
    }
}

__global__ __launch_bounds__(256) void k_idx(const unsigned long long* __restrict__ best,
                                             float* __restrict__ idxf) {
    const int t = blockIdx.x * 256 + threadIdx.x;
    idxf[t] = (float)(unsigned)(best[t] & 0xFFFFFFFFULL);
}

// ===========================================================================
// FALLBACK (round-3 proven path) — used when ws_size < WS_NEED
__global__ __launch_bounds__(512) void k_main_fb(
        const float* __restrict__ x, const float* __restrict__ emb,
        const float* __restrict__ x2, const float* __restrict__ e2,
        float* __restrict__ idxf) {
    __shared__ float xT[32][132];
    __shared__ float eT[32][260];
    const int tid = threadIdx.x;
    const int tx = tid & 31, ty = tid >> 5;
    const int t0 = blockIdx.x * 128;
    float x2r[8];
#pragma unroll
    for (int ii = 0; ii < 8; ++ii)
        x2r[ii] = x2[t0 + ((ii & 4) << 4) + ty * 4 + (ii & 3)];
    float tb[8]; int ti[8];
#pragma unroll
    for (int s = 0; s < 8; ++s) { tb[s] = 3.0e38f; ti[s] = 0; }
    const int xt = tid & 127, xc = tid >> 7;
    const int ev = tid & 255, ec0 = tid >> 8;
    for (int v0 = 0; v0 < VOCAB; v0 += 256) {
        float a[8][8];
#pragma unroll
        for (int i = 0; i < 8; ++i)
#pragma unroll
            for (int j = 0; j < 8; ++j) a[i][j] = 0.0f;
        for (int kk = 0; kk < DIM; kk += 32) {
            __syncthreads();
#pragma unroll
            for (int h = 0; h < 2; ++h) {
                const int kc = h * 16 + xc * 4;
                const float4 vx = *(const float4*)&x[(size_t)(t0 + xt) * DIM + kk + kc];
                xT[kc + 0][xt] = vx.x; xT[kc + 1][xt] = vx.y;
                xT[kc + 2][xt] = vx.z; xT[kc + 3][xt] = vx.w;
            }
#pragma unroll
            for (int h = 0; h < 4; ++h) {
                const int kc = (ec0 + 2 * h) * 4;
                const float4 ve = *(const float4*)&emb[(size_t)(v0 + ev) * DIM + kk + kc];
                eT[kc + 0][ev] = ve.x; eT[kc + 1][ev] = ve.y;
                eT[kc + 2][ev] = ve.z; eT[kc + 3][ev] = ve.w;
            }
            __syncthreads();
#pragma unroll 4
            for (int k = 0; k < 32; ++k) {
                float xa[8], eb[8];
                *(float4*)&xa[0] = *(const float4*)&xT[k][ty * 4];
                *(float4*)&xa[4] = *(const float4*)&xT[k][64 + ty * 4];
                *(float4*)&eb[0] = *(const float4*)&eT[k][tx * 4];
                *(float4*)&eb[4] = *(const float4*)&eT[k][128 + tx * 4];
#pragma unroll
                for (int i = 0; i < 8; ++i)
#pragma unroll
                    for (int j = 0; j < 8; ++j)
                        a[i][j] = fmaf(xa[i], eb[j], a[i][j]);
            }
        }
#pragma unroll
        for (int jj = 0; jj < 8; ++jj) {
            const int v = v0 + ((jj & 4) << 5) + tx * 4 + (jj & 3);
            const float evv = e2[v];
#pragma unroll
            for (int ii = 0; ii < 8; ++ii) {
                const float A  = x2r[ii] + evv;
                const float sc = A - 2.0f * a[ii][jj];
                if (sc < tb[ii]) { tb[ii] = sc; ti[ii] = v; }
            }
        }
    }
#pragma unroll
    for (int ii = 0; ii < 8; ++ii) {
        float b = tb[ii]; int bi = ti[ii];
#pragma unroll
        for (int m = 1; m < 32; m <<= 1) {
            const float ob = __shfl_xor(b, m, 64);
            const int   oi = __shfl_xor(bi, m, 64);
            if (ob < b || (ob == b && oi < bi)) { b = ob; bi = oi; }
        }
        if (tx == 0) {
            const int token = t0 + ((ii & 4) << 4) + ty * 4 + (ii & 3);
            idxf[token] = (float)bi;
        }
    }
}

// ===========================================================================
// gather quantised + loss reduction (shared by both paths)
__global__ __launch_bounds__(256) void k_gather(
        const float* __restrict__ x, const float* __restrict__ emb,
        const float* __restrict__ idxf, float* __restrict__ qout,
        float* __restrict__ acc) {
    const int token = blockIdx.x * 4 + (threadIdx.x >> 6);
    const int lane  = threadIdx.x & 63;
    const int v = (int)idxf[token];
    const float4 e4 = *(const float4*)&emb[(size_t)v * DIM + lane * 4];
    const float4 x4 = *(const float4*)&x[(size_t)token * DIM + lane * 4];
    *(float4*)&qout[(size_t)token * DIM + lane * 4] = e4;
    const float dx = e4.x - x4.x, dy = e4.y - x4.y, dz = e4.z - x4.z, dw = e4.w - x4.w;
    float s = dx*dx + dy*dy + dz*dz + dw*dw;
#pragma unroll
    for (int m = 1; m < 64; m <<= 1) s += __shfl_xor(s, m, 64);
    __shared__ float wsum[4];
    if (lane == 0) wsum[threadIdx.x >> 6] = s;
    __syncthreads();
    if (threadIdx.x == 0) atomicAdd(acc, wsum[0] + wsum[1] + wsum[2] + wsum[3]);
}

__global__ void k_final(const float* __restrict__ acc, float* __restrict__ out) {
    const float cb = *acc * (1.0f / 8388608.0f);
    out[LOSS_OFF] = 1.25f * cb;
    out[CB_OFF]   = cb;
}

// ===========================================================================
extern "C" void kernel_launch(void* const* d_in, const int* in_sizes, int n_in,
                              void* d_out, int out_size, void* d_ws, size_t ws_size,
                              hipStream_t stream) {
    const float* x   = (const float*)d_in[0];
    const float* emb = (const float*)d_in[1];
    float* out  = (float*)d_out;
    char*  wsB  = (char*)d_ws;
    float* wsF  = (float*)d_ws;

    float* x2   = wsF + X2_F;
    float* e2   = wsF + E2_F;
    float* acc  = wsF + ACC_F;
    int*   cnt  = (int*)wsF + CNT_I;
    int*   ovf  = (int*)wsF + OVF_I;
    unsigned long long* best = (unsigned long long*)(wsB + BEST_B);
    unsigned short*     e16  = (unsigned short*)(wsB + EMB16_B);
    float*              smax = (float*)(wsB + SMAX_B);
    unsigned*           binned = (unsigned*)(wsB + SMAX_B);   // reuse after collect
    int*                scnt  = (int*)(wsB + SCNT_B);
    int*                sbase = (int*)(wsB + SBASE_B);
    int*                scur  = (int*)(wsB + SCUR_B);
    unsigned*           list  = (unsigned*)(wsB + LIST_B);
    float* idxf = out + IDX_OFF;

    const int full = (ws_size >= (size_t)WS_NEED) ? 1 : 0;

    k_sums<<<(NTOK + VOCAB) / 16, 256, 0, stream>>>(x, emb, wsF, best, scnt, full);
    if (full) {
        k_cvt     <<<2048, 256, 0, stream>>>(emb, (unsigned*)e16);
        k_coarse  <<<256, 512, 0, stream>>>(x, e16, smax, list, cnt, ovf);
        k_bincount<<<64, 256, 0, stream>>>(list, cnt, scnt);
        k_scan    <<<1, 256, 0, stream>>>(scnt, sbase, scur);
        k_scatter <<<64, 256, 0, stream>>>(list, cnt, scur, binned);
        k_exact2  <<<2048, 256, 0, stream>>>(x, emb, x2, e2, binned, sbase, scnt, ovf, best);
        k_idx     <<<NTOK / 256, 256, 0, stream>>>(best, idxf);
    } else {
        k_main_fb<<<NTOK / 128, 512, 0, stream>>>(x, emb, x2, e2, idxf);
    }
    k_gather<<<NTOK / 4, 256, 0, stream>>>(x, emb, idxf, out, acc);
    k_final <<<1, 1, 0, stream>>>(acc, out);
}

// Round 9
// 404.286 us; speedup vs baseline: 4.5895x; 1.0033x over previous
//
#include <hip/hip_runtime.h>

#define VOCAB 8192
#define DIM   256
#define NTOK  32768          // 8*4096

// d_out layout (floats): quantised[8388608], loss, codebook_loss, idx[32768] (as float)
#define LOSS_OFF 8388608
#define CB_OFF   8388609
#define IDX_OFF  8388610

// ---- ws layout (bytes) ----
#define X2_F     0            // float[32768]   (f32 index)
#define E2_F     32768        // float[8192]
#define ACC_F    40960        // float
#define CNT_I    40961        // int
#define OVF_I    40962        // int
#define BEST_B   196608       // u64[32768]   -> ends 458752
#define EMB16_B  458752       // bf16[8192*256] = 4 MiB -> ends 4653056
#define SMAX_B   4718592      // float[256][32768] = 32 MiB (also reused as binned list)
#define SCNT_B   38273024     // int[256]
#define SBASE_B  38274048     // int[256]
#define SCUR_B   38275072     // int[256]
#define LIST_B   38404096     // u32[CAP]
#define CAP      4194304
#define WS_NEED  (LIST_B + CAP * 4)   // 55,181,312 bytes

#define M2 1.5e-4f            // dot-space rescue margin (err budget ~6e-5 practical)
#define LCAP 16000            // per-block LDS candidate cap (256*16000 < CAP)

typedef __attribute__((ext_vector_type(8)))  short bf16x8;
typedef __attribute__((ext_vector_type(16))) float f32x16;

// ===========================================================================
// k_sums: numpy pairwise-exact x2/e2 (proven round 3) + init scalars/best/scnt
__global__ __launch_bounds__(256) void k_sums(const float* __restrict__ x,
                                              const float* __restrict__ emb,
                                              float* __restrict__ ws,
                                              unsigned long long* __restrict__ best,
                                              int* __restrict__ scnt,
                                              int full) {
    const int lane = threadIdx.x & 63;
    const int wave = threadIdx.x >> 6;
    const int row  = blockIdx.x * 16 + wave * 4 + (lane >> 4);
    const int sub  = lane & 15;
    const int k    = sub & 7;
    const int half = sub >> 3;
    const float* src = (row < NTOK ? x + (size_t)row * DIM
                                   : emb + (size_t)(row - NTOK) * DIM)
                       + half * 128 + k;
    float r;
    {
        float v0 = src[0];
        float t0 = v0 * v0;
        asm volatile("" : "+v"(t0));     // block fma contraction
        r = t0;
        for (int i = 1; i < 16; ++i) {
            float w = src[8 * i];
            float u = w * w;
            asm volatile("" : "+v"(u));
            r = r + u;
        }
    }
    float t;
    t = __shfl_xor(r, 1, 64); r = r + t;
    t = __shfl_xor(r, 2, 64); r = r + t;
    t = __shfl_xor(r, 4, 64); r = r + t;
    t = __shfl_xor(r, 8, 64); r = r + t;
    if (sub == 0) ws[row] = r;
    const int gid = blockIdx.x * 256 + threadIdx.x;
    if (gid == 0) {
        ws[ACC_F] = 0.0f;
        ((int*)ws)[CNT_I] = 0;
        ((int*)ws)[OVF_I] = 0;
    }
    if (full) {
        if (gid < NTOK) best[gid] = ~0ULL;
        if (gid < 256)  scnt[gid] = 0;
    }
}

// ===========================================================================
// k_cvt: emb fp32 -> bf16 (truncate; margin absorbs the bias)
__global__ __launch_bounds__(256) void k_cvt(const float* __restrict__ emb,
                                             unsigned* __restrict__ out) {
    const int i = blockIdx.x * 256 + threadIdx.x;      // 524288 threads x 4 floats
    const float4 f = *(const float4*)(emb + (size_t)i * 4);
    unsigned b0 = __float_as_uint(f.x), b1 = __float_as_uint(f.y);
    unsigned b2 = __float_as_uint(f.z), b3 = __float_as_uint(f.w);
    uint2 o;
    o.x = (b1 & 0xFFFF0000u) | (b0 >> 16);
    o.y = (b3 & 0xFFFF0000u) | (b2 >> 16);
    *(uint2*)(out + (size_t)i * 2) = o;
}

// ===========================================================================
// k_coarse: bf16 MFMA max-dot per (token, 32-code tile), 8-phase-style
// schedule: 4 phases/chunk, each {4 ds_read ∥ 4 stage loads -> barrier ->
// 8 MFMA (setprio) -> barrier}; chunk boundary vmcnt(1) excludes the smax
// store from the wait. 5-bit XOR swizzle both sides (round-7 proven).
#define AS1 __attribute__((address_space(1)))
#define AS3 __attribute__((address_space(3)))

#define STAGE4(BUFI, N, P) do {                                                \
    const char* _src = (const char*)embh + ((size_t)(N) << 16);                \
    char* _dst = ebuf[BUFI];                                                   \
    _Pragma("unroll")                                                          \
    for (int _r = (P) * 4; _r < (P) * 4 + 4; ++_r) {                           \
        const unsigned _o = (unsigned)tid * 16u + (unsigned)_r * 8192u;        \
        __builtin_amdgcn_global_load_lds(                                      \
            (const AS1 void*)(_src + so8[_r]),                                 \
            (AS3 void*)(_dst + _o), 16, 0, 0);                                 \
    }                                                                          \
} while (0)

__device__ __forceinline__ unsigned f_ord(float v) {
    unsigned u = __float_as_uint(v);
    return u ^ ((unsigned)((int)u >> 31) | 0x80000000u);
}
__device__ __forceinline__ float f_unord(unsigned k) {
    unsigned m = (k >> 31) ? 0x80000000u : 0xFFFFFFFFu;
    return __uint_as_float(k ^ m);
}

__global__ __launch_bounds__(512, 2) void k_coarse(
        const float* __restrict__ x, const unsigned short* __restrict__ embh,
        float* __restrict__ smax,
        unsigned* __restrict__ list, int* __restrict__ cnt,
        int* __restrict__ ovf) {
    __shared__ char ebuf[2][65536];
    __shared__ unsigned tmax[128];
    __shared__ float tthr[128];
    __shared__ unsigned gbase, bcnt;

    const int tid  = threadIdx.x;
    const int lane = tid & 63, wid = tid >> 6;
    const int g = wid & 1, csub = wid >> 1;
    const int t_wave = blockIdx.x * 128 + g * 64;

    // hoisted swizzled staging source offsets (loop-invariant)
    unsigned so8[8];
#pragma unroll
    for (int r = 0; r < 8; ++r) {
        const unsigned o = (unsigned)tid * 16u + (unsigned)r * 8192u;
        so8[r] = (o & ~511u) | ((o & 511u) ^ (((o >> 9) & 31u) << 4));
    }

    // ---- persistent x B-frags: bx[grp][kt], token col = lane&31, k = kt*16+(lane>>5)*8+j
    bf16x8 bx[2][16];
    {
        const int tok0 = t_wave + (lane & 31);
#pragma unroll
        for (int grp = 0; grp < 2; ++grp) {
            const float* xr = x + (size_t)(tok0 + grp * 32) * DIM + (lane >> 5) * 8;
#pragma unroll
            for (int kt = 0; kt < 16; ++kt) {
                float4 f0 = *(const float4*)(xr + kt * 16);
                float4 f1 = *(const float4*)(xr + kt * 16 + 4);
                union { bf16x8 v; unsigned u[4]; } P;
                P.u[0] = (__float_as_uint(f0.y) & 0xFFFF0000u) | (__float_as_uint(f0.x) >> 16);
                P.u[1] = (__float_as_uint(f0.w) & 0xFFFF0000u) | (__float_as_uint(f0.z) >> 16);
                P.u[2] = (__float_as_uint(f1.y) & 0xFFFF0000u) | (__float_as_uint(f1.x) >> 16);
                P.u[3] = (__float_as_uint(f1.w) & 0xFFFF0000u) | (__float_as_uint(f1.z) >> 16);
                bx[grp][kt] = P.v;
            }
        }
    }

    // A-read: row rl = csub*32 + lane&31, col bytes = kt*32 + (lane>>5)*16
    const unsigned rl    = (unsigned)(csub * 32 + (lane & 31));
    const unsigned abase = rl * 512u + (unsigned)((lane >> 5) * 16);
    const unsigned sw    = (rl & 31u) << 4;     // 5-bit XOR: 32 distinct slots

    STAGE4(0, 0, 0);
    STAGE4(0, 0, 1);
    asm volatile("s_waitcnt vmcnt(0)" ::: "memory");
    __builtin_amdgcn_s_barrier();

    float rmax = -3.0e38f;
    for (int n = 0; n < 64; ++n) {
        const char* cb = ebuf[n & 1];
        const int   nb = (n + 1) & 1;
        const bool  more = (n + 1 < 64);

        f32x16 acc0, acc1;
#pragma unroll
        for (int q = 0; q < 16; ++q) { acc0[q] = 0.0f; acc1[q] = 0.0f; }

#pragma unroll
        for (int p = 0; p < 4; ++p) {
            // 4 ds_read af for this phase's kt group
            bf16x8 a0 = *(const bf16x8*)(cb + ((abase + (unsigned)(p * 4 + 0) * 32u) ^ sw));
            bf16x8 a1 = *(const bf16x8*)(cb + ((abase + (unsigned)(p * 4 + 1) * 32u) ^ sw));
            bf16x8 a2 = *(const bf16x8*)(cb + ((abase + (unsigned)(p * 4 + 2) * 32u) ^ sw));
            bf16x8 a3 = *(const bf16x8*)(cb + ((abase + (unsigned)(p * 4 + 3) * 32u) ^ sw));
            // stage next chunk early (phases 0-1 -> >=2 phases of slack)
            if (more && p < 2) STAGE4(nb, n + 1, p);
            __builtin_amdgcn_s_barrier();
            __builtin_amdgcn_s_setprio(1);
            acc0 = __builtin_amdgcn_mfma_f32_32x32x16_bf16(a0, bx[0][p * 4 + 0], acc0, 0, 0, 0);
            acc1 = __builtin_amdgcn_mfma_f32_32x32x16_bf16(a0, bx[1][p * 4 + 0], acc1, 0, 0, 0);
            acc0 = __builtin_amdgcn_mfma_f32_32x32x16_bf16(a1, bx[0][p * 4 + 1], acc0, 0, 0, 0);
            acc1 = __builtin_amdgcn_mfma_f32_32x32x16_bf16(a1, bx[1][p * 4 + 1], acc1, 0, 0, 0);
            acc0 = __builtin_amdgcn_mfma_f32_32x32x16_bf16(a2, bx[0][p * 4 + 2], acc0, 0, 0, 0);
            acc1 = __builtin_amdgcn_mfma_f32_32x32x16_bf16(a2, bx[1][p * 4 + 2], acc1, 0, 0, 0);
            acc0 = __builtin_amdgcn_mfma_f32_32x32x16_bf16(a3, bx[0][p * 4 + 3], acc0, 0, 0, 0);
            acc1 = __builtin_amdgcn_mfma_f32_32x32x16_bf16(a3, bx[1][p * 4 + 3], acc1, 0, 0, 0);
            __builtin_amdgcn_s_setprio(0);
            __builtin_amdgcn_s_barrier();
        }

        // max over the 16 rows each lane holds (max3-friendly), merge halves
        float m0, m1;
        {
            float a = fmaxf(fmaxf(acc0[0], acc0[1]),  fmaxf(acc0[2], acc0[3]));
            float b = fmaxf(fmaxf(acc0[4], acc0[5]),  fmaxf(acc0[6], acc0[7]));
            float c = fmaxf(fmaxf(acc0[8], acc0[9]),  fmaxf(acc0[10], acc0[11]));
            float d = fmaxf(fmaxf(acc0[12], acc0[13]),fmaxf(acc0[14], acc0[15]));
            m0 = fmaxf(fmaxf(a, b), fmaxf(c, d));
            a = fmaxf(fmaxf(acc1[0], acc1[1]),  fmaxf(acc1[2], acc1[3]));
            b = fmaxf(fmaxf(acc1[4], acc1[5]),  fmaxf(acc1[6], acc1[7]));
            c = fmaxf(fmaxf(acc1[8], acc1[9]),  fmaxf(acc1[10], acc1[11]));
            d = fmaxf(fmaxf(acc1[12], acc1[13]),fmaxf(acc1[14], acc1[15]));
            m1 = fmaxf(fmaxf(a, b), fmaxf(c, d));
        }
        m0 = fmaxf(m0, __shfl_xor(m0, 32, 64));
        m1 = fmaxf(m1, __shfl_xor(m1, 32, 64));
        const float mv = (lane < 32) ? m0 : m1;      // token = t_wave + lane
        rmax = fmaxf(rmax, mv);
        smax[(size_t)(n * 4 + csub) * NTOK + t_wave + lane] = mv;

        // chunk boundary: retire exactly stage(n+1)'s 8 loads; store stays in flight
        if (more) asm volatile("s_waitcnt vmcnt(1)" ::: "memory");
        else      asm volatile("s_waitcnt vmcnt(0)" ::: "memory");
        __builtin_amdgcn_s_barrier();
    }

    // ---- per-token threshold = gmax - M2 (cross-wave merge in LDS)
    unsigned* lbuf = (unsigned*)ebuf;          // main loop done: reuse as list
    if (tid < 128) tmax[tid] = 0u;
    if (tid == 0) { lbuf[0] = 0u; }
    __syncthreads();
    atomicMax(&tmax[g * 64 + lane], f_ord(rmax));
    __syncthreads();
    if (tid < 128) tthr[tid] = f_unord(tmax[tid]) - M2;
    __syncthreads();

    // ---- fused collect: re-read own smax slice, compact in LDS
    const int t0b = blockIdx.x * 128;
    for (int r = 0; r < 64; ++r) {
        const int cell  = r * 512 + tid;       // 0..32767
        const int stile = cell >> 7, tl = cell & 127;
        const float v = smax[(size_t)stile * NTOK + t0b + tl];
        if (v >= tthr[tl]) {
            const unsigned p = atomicAdd(&lbuf[0], 1u);
            if (p < LCAP)
                lbuf[2 + p] = ((unsigned)(t0b + tl) << 8) | (unsigned)stile;
        }
    }
    __syncthreads();
    if (tid == 0) {
        unsigned bc = lbuf[0];
        if (bc > LCAP) { bc = LCAP; *ovf = 1; }
        bcnt  = bc;
        gbase = (unsigned)atomicAdd(cnt, (int)bc);   // ONE global atomic per block
    }
    __syncthreads();
    const unsigned bc = bcnt, gb = gbase;
    for (unsigned i = tid; i < bc; i += 512) list[gb + i] = lbuf[2 + i];
}

// ===========================================================================
// Binning: count per stile -> scan -> scatter into per-stile buckets
__global__ __launch_bounds__(256) void k_bincount(const unsigned* __restrict__ list,
                                                  const int* __restrict__ cnt,
                                                  int* __restrict__ scnt) {
    __shared__ int lc[256];
    lc[threadIdx.x] = 0;
    __syncthreads();
    int n = *cnt; if (n > CAP) n = CAP;
    for (int i = blockIdx.x * 256 + threadIdx.x; i < n; i += 64 * 256)
        atomicAdd(&lc[list[i] & 255u], 1);
    __syncthreads();
    if (lc[threadIdx.x]) atomicAdd(&scnt[threadIdx.x], lc[threadIdx.x]);
}

__global__ __launch_bounds__(256) void k_scan(const int* __restrict__ scnt,
                                              int* __restrict__ sbase,
                                              int* __restrict__ scur) {
    __shared__ int a[256], b[256];
    const int t = threadIdx.x;
    a[t] = scnt[t];
    __syncthreads();
    int* src = a; int* dst = b;
    for (int off = 1; off < 256; off <<= 1) {
        dst[t] = src[t] + ((t >= off) ? src[t - off] : 0);
        __syncthreads();
        int* tp = src; src = dst; dst = tp;
    }
    const int excl = src[t] - scnt[t];
    sbase[t] = excl;
    scur[t]  = excl;
}

__global__ __launch_bounds__(256) void k_scatter(const unsigned* __restrict__ list,
                                                 const int* __restrict__ cnt,
                                                 int* __restrict__ scur,
                                                 unsigned* __restrict__ binned) {
    int n = *cnt; if (n > CAP) n = CAP;
    for (int i = blockIdx.x * 256 + threadIdx.x; i < n; i += 64 * 256) {
        const unsigned e = list[i];
        const int p = atomicAdd(&scur[e & 255u], 1);
        binned[p] = e;
    }
}

// ===========================================================================
// k_exact2: per-stile buckets, emb tile in LDS, ref-bit-identical fp32 score
__device__ __forceinline__ float exact_score(const float* __restrict__ xr,
                                             const float* __restrict__ er,
                                             float x2t, float e2v) {
    float dot = 0.0f;
#pragma unroll 16
    for (int d = 0; d < DIM; d += 4) {
        const float4 e4 = *(const float4*)(er + d);
        const float4 x4 = *(const float4*)(xr + d);
        dot = fmaf(e4.x, x4.x, dot);
        dot = fmaf(e4.y, x4.y, dot);
        dot = fmaf(e4.z, x4.z, dot);
        dot = fmaf(e4.w, x4.w, dot);
    }
    const float A = x2t + e2v;          // fl(x2 + e2)
    return A - 2.0f * dot;              // fl(A - fl(2*dot)); 2*dot exact
}

__global__ __launch_bounds__(256) void k_exact2(
        const float* __restrict__ x, const float* __restrict__ emb,
        const float* __restrict__ x2, const float* __restrict__ e2,
        const unsigned* __restrict__ binned, const int* __restrict__ sbase,
        const int* __restrict__ scnt, const int* __restrict__ ovf,
        unsigned long long* __restrict__ best) {
    __shared__ float elds[32][257];
    __shared__ float e2s[32];
    const int s = blockIdx.x >> 3, sub = blockIdx.x & 7;
    {   // stage this stile's 32 emb rows (fp32) into LDS
        const int r = threadIdx.x >> 3, c0 = (threadIdx.x & 7) * 32;
        const float* er = emb + (size_t)(s * 32 + r) * DIM + c0;
#pragma unroll
        for (int q = 0; q < 8; ++q) {
            const float4 f = *(const float4*)(er + q * 4);
            elds[r][c0 + q * 4 + 0] = f.x; elds[r][c0 + q * 4 + 1] = f.y;
            elds[r][c0 + q * 4 + 2] = f.z; elds[r][c0 + q * 4 + 3] = f.w;
        }
        if (threadIdx.x < 32) e2s[threadIdx.x] = e2[s * 32 + threadIdx.x];
    }
    __syncthreads();

    const int lane = threadIdx.x & 63, wave = threadIdx.x >> 6;
    const int l5 = lane & 31, half = lane >> 5;
    const int base = sbase[s], count = scnt[s];
    const float e2v = e2s[l5];

    for (int k = (sub * 4 + wave) * 2 + half; k < count; k += 64) {
        const unsigned e = binned[base + k];
        const int token  = (int)(e >> 8);
        const float* xr  = x + (size_t)token * DIM;
        const float x2t  = x2[token];
        // sequential fmaf chain, d ascending, x/y/z/w order == proven ref semantics
        float dot = 0.0f;
#pragma unroll 16
        for (int d = 0; d < DIM; d += 4) {
            const float4 x4 = *(const float4*)(xr + d);
            dot = fmaf(elds[l5][d + 0], x4.x, dot);
            dot = fmaf(elds[l5][d + 1], x4.y, dot);
            dot = fmaf(elds[l5][d + 2], x4.z, dot);
            dot = fmaf(elds[l5][d + 3], x4.w, dot);
        }
        const float A  = x2t + e2v;
        const float sc = A - 2.0f * dot;
        unsigned long long pk =
            ((unsigned long long)__float_as_uint(sc) << 32) | (unsigned)(s * 32 + l5);
#pragma unroll
        for (int m = 1; m < 32; m <<= 1) {   // stays within the 32-lane half
            unsigned long long o = __shfl_xor(pk, m, 64);
            if (o < pk) pk = o;
        }
        if (l5 == 0) atomicMin(&best[token], pk);
    }

    if (*ovf) {   // exhaustive safety net (never expected)
        const size_t stride = (size_t)2048 * 256;
        for (size_t c = blockIdx.x * 256 + threadIdx.x;
             c < (size_t)NTOK * VOCAB; c += stride) {
            const int token = (int)(c >> 13);
            const int v     = (int)(c & (VOCAB - 1));
            const float sc = exact_score(x + (size_t)token * DIM, emb + (size_t)v * DIM,
                                         x2[token], e2[v]);
            unsigned long long pk =
                ((unsigned long long)__float_as_uint(sc) << 32) | (unsigned)v;
            atomicMin(&best[token], pk);
        }
    }
}

__global__ __launch_bounds__(256) void k_idx(const unsigned long long* __restrict__ best,
                                             float* __restrict__ idxf) {
    const int t = blockIdx.x * 256 + threadIdx.x;
    idxf[t] = (float)(unsigned)(best[t] & 0xFFFFFFFFULL);
}

// ===========================================================================
// FALLBACK (round-3 proven path) — used when ws_size < WS_NEED
__global__ __launch_bounds__(512) void k_main_fb(
        const float* __restrict__ x, const float* __restrict__ emb,
        const float* __restrict__ x2, const float* __restrict__ e2,
        float* __restrict__ idxf) {
    __shared__ float xT[32][132];
    __shared__ float eT[32][260];
    const int tid = threadIdx.x;
    const int tx = tid & 31, ty = tid >> 5;
    const int t0 = blockIdx.x * 128;
    float x2r[8];
#pragma unroll
    for (int ii = 0; ii < 8; ++ii)
        x2r[ii] = x2[t0 + ((ii & 4) << 4) + ty * 4 + (ii & 3)];
    float tb[8]; int ti[8];
#pragma unroll
    for (int s = 0; s < 8; ++s) { tb[s] = 3.0e38f; ti[s] = 0; }
    const int xt = tid & 127, xc = tid >> 7;
    const int ev = tid & 255, ec0 = tid >> 8;
    for (int v0 = 0; v0 < VOCAB; v0 += 256) {
        float a[8][8];
#pragma unroll
        for (int i = 0; i < 8; ++i)
#pragma unroll
            for (int j = 0; j < 8; ++j) a[i][j] = 0.0f;
        for (int kk = 0; kk < DIM; kk += 32) {
            __syncthreads();
#pragma unroll
            for (int h = 0; h < 2; ++h) {
                const int kc = h * 16 + xc * 4;
                const float4 vx = *(const float4*)&x[(size_t)(t0 + xt) * DIM + kk + kc];
                xT[kc + 0][xt] = vx.x; xT[kc + 1][xt] = vx.y;
                xT[kc + 2][xt] = vx.z; xT[kc + 3][xt] = vx.w;
            }
#pragma unroll
            for (int h = 0; h < 4; ++h) {
                const int kc = (ec0 + 2 * h) * 4;
                const float4 ve = *(const float4*)&emb[(size_t)(v0 + ev) * DIM + kk + kc];
                eT[kc + 0][ev] = ve.x; eT[kc + 1][ev] = ve.y;
                eT[kc + 2][ev] = ve.z; eT[kc + 3][ev] = ve.w;
            }
            __syncthreads();
#pragma unroll 4
            for (int k = 0; k < 32; ++k) {
                float xa[8], eb[8];
                *(float4*)&xa[0] = *(const float4*)&xT[k][ty * 4];
                *(float4*)&xa[4] = *(const float4*)&xT[k][64 + ty * 4];
                *(float4*)&eb[0] = *(const float4*)&eT[k][tx * 4];
                *(float4*)&eb[4] = *(const float4*)&eT[k][128 + tx * 4];
#pragma unroll
                for (int i = 0; i < 8; ++i)
#pragma unroll
                    for (int j = 0; j < 8; ++j)
                        a[i][j] = fmaf(xa[i], eb[j], a[i][j]);
            }
        }
#pragma unroll
        for (int jj = 0; jj < 8; ++jj) {
            const int v = v0 + ((jj & 4) << 5) + tx * 4 + (jj & 3);
            const float evv = e2[v];
#pragma unroll
            for (int ii = 0; ii < 8; ++ii) {
                const float A  = x2r[ii] + evv;
                const float sc = A - 2.0f * a[ii][jj];
                if (sc < tb[ii]) { tb[ii] = sc; ti[ii] = v; }
            }
        }
    }
#pragma unroll
    for (int ii = 0; ii < 8; ++ii) {
        float b = tb[ii]; int bi = ti[ii];
#pragma unroll
        for (int m = 1; m < 32; m <<= 1) {
            const float ob = __shfl_xor(b, m, 64);
            const int   oi = __shfl_xor(bi, m, 64);
            if (ob < b || (ob == b && oi < bi)) { b = ob; bi = oi; }
        }
        if (tx == 0) {
            const int token = t0 + ((ii & 4) << 4) + ty * 4 + (ii & 3);
            idxf[token] = (float)bi;
        }
    }
}

// ===========================================================================
// gather quantised + loss reduction (shared by both paths)
__global__ __launch_bounds__(256) void k_gather(
        const float* __restrict__ x, const float* __restrict__ emb,
        const float* __restrict__ idxf, float* __restrict__ qout,
        float* __restrict__ acc) {
    const int token = blockIdx.x * 4 + (threadIdx.x >> 6);
    const int lane  = threadIdx.x & 63;
    const int v = (int)idxf[token];
    const float4 e4 = *(const float4*)&emb[(size_t)v * DIM + lane * 4];
    const float4 x4 = *(const float4*)&x[(size_t)token * DIM + lane * 4];
    *(float4*)&qout[(size_t)token * DIM + lane * 4] = e4;
    const float dx = e4.x - x4.x, dy = e4.y - x4.y, dz = e4.z - x4.z, dw = e4.w - x4.w;
    float s = dx*dx + dy*dy + dz*dz + dw*dw;
#pragma unroll
    for (int m = 1; m < 64; m <<= 1) s += __shfl_xor(s, m, 64);
    __shared__ float wsum[4];
    if (lane == 0) wsum[threadIdx.x >> 6] = s;
    __syncthreads();
    if (threadIdx.x == 0) atomicAdd(acc, wsum[0] + wsum[1] + wsum[2] + wsum[3]);
}

__global__ void k_final(const float* __restrict__ acc, float* __restrict__ out) {
    const float cb = *acc * (1.0f / 8388608.0f);
    out[LOSS_OFF] = 1.25f * cb;
    out[CB_OFF]   = cb;
}

// ===========================================================================
extern "C" void kernel_launch(void* const* d_in, const int* in_sizes, int n_in,
                              void* d_out, int out_size, void* d_ws, size_t ws_size,
                              hipStream_t stream) {
    const float* x   = (const float*)d_in[0];
    const float* emb = (const float*)d_in[1];
    float* out  = (float*)d_out;
    char*  wsB  = (char*)d_ws;
    float* wsF  = (float*)d_ws;

    float* x2   = wsF + X2_F;
    float* e2   = wsF + E2_F;
    float* acc  = wsF + ACC_F;
    int*   cnt  = (int*)wsF + CNT_I;
    int*   ovf  = (int*)wsF + OVF_I;
    unsigned long long* best = (unsigned long long*)(wsB + BEST_B);
    unsigned short*     e16  = (unsigned short*)(wsB + EMB16_B);
    float*              smax = (float*)(wsB + SMAX_B);
    unsigned*           binned = (unsigned*)(wsB + SMAX_B);   // reuse after collect
    int*                scnt  = (int*)(wsB + SCNT_B);
    int*                sbase = (int*)(wsB + SBASE_B);
    int*                scur  = (int*)(wsB + SCUR_B);
    unsigned*           list  = (unsigned*)(wsB + LIST_B);
    float* idxf = out + IDX_OFF;

    const int full = (ws_size >= (size_t)WS_NEED) ? 1 : 0;

    k_sums<<<(NTOK + VOCAB) / 16, 256, 0, stream>>>(x, emb, wsF, best, scnt, full);
    if (full) {
        k_cvt     <<<2048, 256, 0, stream>>>(emb, (unsigned*)e16);
        k_coarse  <<<256, 512, 0, stream>>>(x, e16, smax, list, cnt, ovf);
        k_bincount<<<64, 256, 0, stream>>>(list, cnt, scnt);
        k_scan    <<<1, 256, 0, stream>>>(scnt, sbase, scur);
        k_scatter <<<64, 256, 0, stream>>>(list, cnt, scur, binned);
        k_exact2  <<<2048, 256, 0, stream>>>(x, emb, x2, e2, binned, sbase, scnt, ovf, best);
        k_idx     <<<NTOK / 256, 256, 0, stream>>>(best, idxf);
    } else {
        k_main_fb<<<NTOK / 128, 512, 0, stream>>>(x, emb, x2, e2, idxf);
    }
    k_gather<<<NTOK / 4, 256, 0, stream>>>(x, emb, idxf, out, acc);
    k_final <<<1, 1, 0, stream>>>(acc, out);
}